// Round 11
// baseline (313.713 us; speedup 1.0000x reference)
//
#include <hip/hip_runtime.h>
#include <hip/hip_bf16.h>
#include <math.h>

#define BB 2
#define SS 2048
#define NN 2049
#define MM (BB*NN)      // 4098 rows
#define DD 256
#define HR 128          // HEADS*RANK
#define NHEAD 4
#define DFF 512
#define EPSF 1e-6f
#define TB8 257
#define NTILE 514
#define MBLK 129        // merged layer blocks (4 tiles each)
#define EMB_BLKS 1025   // ceil(MM/4)

typedef __attribute__((ext_vector_type(8))) short bf16x8;
typedef __attribute__((ext_vector_type(4))) float f32x4;

// ---------- helpers ----------
__device__ __forceinline__ float wave_sum(float v) {
    v += __shfl_down(v, 32, 64); v += __shfl_down(v, 16, 64);
    v += __shfl_down(v, 8, 64);  v += __shfl_down(v, 4, 64);
    v += __shfl_down(v, 2, 64);  v += __shfl_down(v, 1, 64);
    return v;
}
__device__ __forceinline__ float wave_max(float v) {
    v = fmaxf(v, __shfl_down(v, 32, 64)); v = fmaxf(v, __shfl_down(v, 16, 64));
    v = fmaxf(v, __shfl_down(v, 8, 64));  v = fmaxf(v, __shfl_down(v, 4, 64));
    v = fmaxf(v, __shfl_down(v, 2, 64));  v = fmaxf(v, __shfl_down(v, 1, 64));
    return v;
}
__device__ __forceinline__ float sgnf(float x) {
    return (x > 0.f) ? 1.f : ((x < 0.f) ? -1.f : 0.f);
}
__device__ __forceinline__ ushort f2b(float x) {
    __hip_bfloat16 h = __float2bfloat16(x);
    return *(ushort*)&h;
}
__device__ __forceinline__ float b2f(ushort u) {
    unsigned int v = ((unsigned int)u) << 16;
    return *(float*)&v;
}
__device__ __forceinline__ void split3(float x, ushort& h, ushort& m, ushort& l) {
    h = f2b(x);
    float r1 = x - b2f(h);
    m = f2b(r1);
    l = f2b(r1 - b2f(m));
}
__device__ __forceinline__ void pack_map(int e, int N, int& k, int& n) {
    int j = e & 7;
    int l = (e >> 3) & 63;
    int c = e >> 9;
    int ntiles = N >> 4;
    int kt = c / ntiles, nt = c - kt * ntiles;
    k = kt * 32 + ((l >> 4) << 3) + j;
    n = nt * 16 + (l & 15);
}

// =================== shared phase bodies ===================

__device__ __forceinline__ void pack_job(int idx,
    const float* __restrict__ W1, const float* __restrict__ W2,
    const float* __restrict__ U,  const float* __restrict__ V,
    ushort* __restrict__ W1ph, ushort* __restrict__ W1pl,
    ushort* __restrict__ W2ph, ushort* __restrict__ W2pl,
    ushort* __restrict__ U0, ushort* __restrict__ U1, ushort* __restrict__ U2,
    ushort* __restrict__ V0, ushort* __restrict__ V1, ushort* __restrict__ V2)
{
    int l = idx / 327680;
    int r = idx - l * 327680;
    if (l >= 3) return;
    int k, n;
    if (r < 131072) {
        int e = r;
        pack_map(e, 512, k, n);
        float s = W1[(size_t)l * 131072 + (size_t)k * 512 + n];
        ushort h = f2b(s);
        W1ph[(size_t)l * 131072 + e] = h;
        W1pl[(size_t)l * 131072 + e] = f2b(s - b2f(h));
    } else if (r < 262144) {
        int e = r - 131072;
        pack_map(e, 256, k, n);
        float s = W2[(size_t)l * 131072 + (size_t)k * 256 + n];
        ushort h = f2b(s);
        W2ph[(size_t)l * 131072 + e] = h;
        W2pl[(size_t)l * 131072 + e] = f2b(s - b2f(h));
    } else if (r < 294912) {
        int e = r - 262144;
        pack_map(e, 128, k, n);
        ushort h, m, lo;
        split3(U[(size_t)l * 32768 + (size_t)k * 128 + n], h, m, lo);
        U0[(size_t)l * 32768 + e] = h;
        U1[(size_t)l * 32768 + e] = m;
        U2[(size_t)l * 32768 + e] = lo;
    } else {
        int e = r - 294912;
        pack_map(e, 128, k, n);
        ushort h, m, lo;
        split3(V[(size_t)l * 32768 + (size_t)k * 128 + n], h, m, lo);
        V0[(size_t)l * 32768 + e] = h;
        V1[(size_t)l * 32768 + e] = m;
        V2[(size_t)l * 32768 + e] = lo;
    }
}

__device__ __forceinline__ void state_job(int b, int t, float* red,
    const float* __restrict__ state_in, const float* __restrict__ dstate,
    float* __restrict__ state_out)
{
    float lmax = -INFINITY;
    for (int n = t; n < NN; n += 256) {
        float x = state_in[b * NN + n] + dstate[b * NN + n];
        lmax = fmaxf(lmax, fabsf(x));
    }
    lmax = wave_max(lmax);
    if ((t & 63) == 0) red[t >> 6] = lmax;
    __syncthreads();
    float m = fmaxf(fmaxf(red[0], red[1]), fmaxf(red[2], red[3]));
    float lsum = 0.f;
    for (int n = t; n < NN; n += 256)
        lsum += expf(fabsf(state_in[b * NN + n] + dstate[b * NN + n]) - m);
    lsum = wave_sum(lsum);
    __syncthreads();
    if ((t & 63) == 0) red[4 + (t >> 6)] = lsum;
    __syncthreads();
    float inv = 1.f / (red[4] + red[5] + red[6] + red[7]);
    for (int n = t; n < NN; n += 256) {
        float x = state_in[b * NN + n] + dstate[b * NN + n];
        state_out[b * NN + n] = sgnf(x) * expf(fabsf(x) - m) * inv;
    }
}

// =================== pre: embed (4 rows/block) + weight pack ===================

__global__ void pre_kernel(const int* __restrict__ ids, const float* __restrict__ emb,
                           const float* __restrict__ pos, const float* __restrict__ anchor_val,
                           const float* __restrict__ anchor_state, const float* __restrict__ Ws,
                           const float* __restrict__ bs, float* __restrict__ val,
                           float* __restrict__ state,
                           const float* __restrict__ W1, const float* __restrict__ W2,
                           const float* __restrict__ U,  const float* __restrict__ V,
                           ushort* W1ph, ushort* W1pl, ushort* W2ph, ushort* W2pl,
                           ushort* U0, ushort* U1, ushort* U2,
                           ushort* V0, ushort* V1, ushort* V2) {
    int bid = blockIdx.x;
    int t = threadIdx.x;
    if (bid < EMB_BLKS) {
        int w = t >> 6, l = t & 63;
        int row = bid * 4 + w;
        if (row >= MM) return;
        int b = row / NN, n = row % NN;
        f32x4 e;
        if (n == 0) {
            e = *(const f32x4*)(anchor_val + l * 4);
        } else {
            int id = ids[b * SS + (n - 1)];
            f32x4 em = *(const f32x4*)(emb + (size_t)id * DD + l * 4);
            f32x4 po = *(const f32x4*)(pos + (size_t)(n - 1) * DD + l * 4);
            e = em + po;
        }
        f32x4 wv = *(const f32x4*)(Ws + l * 4);
        float ss = e[0]*e[0] + e[1]*e[1] + e[2]*e[2] + e[3]*e[3];
        float ts = e[0]*wv[0] + e[1]*wv[1] + e[2]*wv[2] + e[3]*wv[3];
        #pragma unroll
        for (int off = 1; off < 64; off <<= 1) {
            ss += __shfl_xor(ss, off, 64);
            ts += __shfl_xor(ts, off, 64);
        }
        float rn = 1.f / fmaxf(sqrtf(ss), EPSF);
        f32x4 o;
        o[0] = e[0] * rn; o[1] = e[1] * rn; o[2] = e[2] * rn; o[3] = e[3] * rn;
        *(f32x4*)(val + (size_t)row * DD + l * 4) = o;
        if (l == 0) state[row] = (n == 0) ? anchor_state[0] : (ts + bs[0]);
        return;
    }
    int base = (bid - EMB_BLKS) * 1024 + t;
    #pragma unroll
    for (int k = 0; k < 4; k++)
        pack_job(base + k * 256, W1, W2, U, V,
                 W1ph, W1pl, W2ph, W2pl, U0, U1, U2, V0, V1, V2);
}

// =================== proj0: layer-0 q/k projection ===================

__global__ __launch_bounds__(256, 3)
void proj_kernel(const float* __restrict__ Xin,
                 const ushort* __restrict__ U0, const ushort* __restrict__ U1,
                 const ushort* __restrict__ U2,
                 const ushort* __restrict__ V0, const ushort* __restrict__ V1,
                 const ushort* __restrict__ V2,
                 ushort* __restrict__ q0, ushort* __restrict__ q1,
                 ushort* __restrict__ q2,
                 ushort* __restrict__ k0, ushort* __restrict__ k1,
                 ushort* __restrict__ k2) {
    __shared__ __align__(16) char smem[24576];
    int t = threadIdx.x;
    int w = t >> 6, l = t & 63;
    int lm = l & 15, quad = l >> 4;
    int m0 = blockIdx.x * 16;
    bool isQ = (blockIdx.y == 0);
    const ushort* P0 = isQ ? U0 : V0;
    const ushort* P1 = isQ ? U1 : V1;
    const ushort* P2 = isQ ? U2 : V2;

    #pragma unroll
    for (int rr = 0; rr < 4; rr++) {
        int row = w * 4 + rr;
        int tok = m0 + row; if (tok > MM - 1) tok = MM - 1;
        f32x4 x = *(const f32x4*)(Xin + (size_t)tok * DD + l * 4);
        ushort4 h4, m4, l4;
        ushort hh, mm, ll;
        split3(x[0], hh, mm, ll); h4.x = hh; m4.x = mm; l4.x = ll;
        split3(x[1], hh, mm, ll); h4.y = hh; m4.y = mm; l4.y = ll;
        split3(x[2], hh, mm, ll); h4.z = hh; m4.z = mm; l4.z = ll;
        split3(x[3], hh, mm, ll); h4.w = hh; m4.w = mm; l4.w = ll;
        unsigned byte = ((unsigned)(row * 512 + l * 8)) ^ ((unsigned)((row & 7) << 4));
        *(ushort4*)(smem + 0 * 8192 + byte) = h4;
        *(ushort4*)(smem + 1 * 8192 + byte) = m4;
        *(ushort4*)(smem + 2 * 8192 + byte) = l4;
    }
    __syncthreads();

    f32x4 acc[2];
    acc[0] = (f32x4)(0.f); acc[1] = (f32x4)(0.f);
    #pragma unroll
    for (int kt = 0; kt < 8; kt++) {
        unsigned abyte = ((unsigned)(lm * 512 + kt * 64 + quad * 16)) ^
                         ((unsigned)((lm & 7) << 4));
        bf16x8 a0 = *(const bf16x8*)(smem + 0 * 8192 + abyte);
        bf16x8 a1 = *(const bf16x8*)(smem + 1 * 8192 + abyte);
        bf16x8 a2 = *(const bf16x8*)(smem + 2 * 8192 + abyte);
        #pragma unroll
        for (int jj = 0; jj < 2; jj++) {
            int ntl = w * 2 + jj;
            size_t off = ((size_t)(kt * 8 + ntl) * 64 + l) * 8;
            bf16x8 b0 = *(const bf16x8*)(P0 + off);
            bf16x8 b1 = *(const bf16x8*)(P1 + off);
            bf16x8 b2 = *(const bf16x8*)(P2 + off);
            acc[jj] = __builtin_amdgcn_mfma_f32_16x16x32_bf16(a0, b0, acc[jj], 0, 0, 0);
            acc[jj] = __builtin_amdgcn_mfma_f32_16x16x32_bf16(a0, b1, acc[jj], 0, 0, 0);
            acc[jj] = __builtin_amdgcn_mfma_f32_16x16x32_bf16(a1, b0, acc[jj], 0, 0, 0);
            acc[jj] = __builtin_amdgcn_mfma_f32_16x16x32_bf16(a1, b1, acc[jj], 0, 0, 0);
            acc[jj] = __builtin_amdgcn_mfma_f32_16x16x32_bf16(a0, b2, acc[jj], 0, 0, 0);
            acc[jj] = __builtin_amdgcn_mfma_f32_16x16x32_bf16(a2, b0, acc[jj], 0, 0, 0);
        }
    }
    ushort* o0 = isQ ? q0 : k0;
    ushort* o1 = isQ ? q1 : k1;
    ushort* o2 = isQ ? q2 : k2;
    #pragma unroll
    for (int jj = 0; jj < 2; jj++) {
        int n = (w * 2 + jj) * 16 + lm;
        #pragma unroll
        for (int r = 0; r < 4; r++) {
            int tok = m0 + quad * 4 + r;
            if (tok < MM) {
                ushort h, m, lo;
                split3(acc[jj][r], h, m, lo);
                size_t oi = (size_t)tok * HR + n;
                o0[oi] = h; o1[oi] = m; o2[oi] = lo;
            }
        }
    }
}

// =================== state: signed softmax (2 blocks x 256) ===================

__global__ void state_kernel(const float* __restrict__ s_in,
                             const float* __restrict__ dstate,
                             float* __restrict__ s_out) {
    __shared__ float red[8];
    state_job(blockIdx.x, threadIdx.x, red, s_in, dstate, s_out);
}

// =================== layer: attn(4 tiles) + ffn1 + ffn2 + norm + proj(next) ===================
// 129 blocks x 1024 threads. Block owns attn tiles 4*bid..4*bid+3 (clamped),
// i.e. 32 row-slots. valB/vb planes live only in LDS.
// LDS (132096 B): attn: sc4[4][18944] @0 | wgt2[4][6912] @75776 | red @131072
//   post-attn (aliasing sc4): valB[32][1024] @0 | vbH @32768 | vbM @49152
//   ffn: Hh @65536(+g*16384) | Hl @98304(+g*16384) | Y @32768(+g*16384)
//   phase C planes @65536 + g*24576.

__global__ __launch_bounds__(1024, 1)
void layer_kernel(const float* __restrict__ valA, const float* __restrict__ s_in,
                  const ushort* __restrict__ q0, const ushort* __restrict__ q1,
                  const ushort* __restrict__ q2,
                  const ushort* __restrict__ k0, const ushort* __restrict__ k1,
                  const ushort* __restrict__ k2,
                  const ushort* __restrict__ W1h, const ushort* __restrict__ W1l,
                  const float*  __restrict__ b1,
                  const ushort* __restrict__ W2h, const ushort* __restrict__ W2l,
                  const float*  __restrict__ b2,
                  const ushort* __restrict__ U0, const ushort* __restrict__ U1,
                  const ushort* __restrict__ U2,
                  const ushort* __restrict__ V0, const ushort* __restrict__ V1,
                  const ushort* __restrict__ V2,
                  ushort* __restrict__ oq0, ushort* __restrict__ oq1,
                  ushort* __restrict__ oq2,
                  ushort* __restrict__ ok0, ushort* __restrict__ ok1,
                  ushort* __restrict__ ok2,
                  float* __restrict__ valA_out, float* __restrict__ dstate_out,
                  float* __restrict__ out2, int last)
{
    __shared__ __align__(16) char smem[132096];
    int t = threadIdx.x;
    int bid = blockIdx.x;

    // ---------------- attention: 4 tiles, 256 threads each ----------------
    int tb4 = t >> 8;
    int tl  = t & 255;
    int tile = 4 * bid + tb4;
    int treal = (tile < NTILE) ? tile : (NTILE - 1);
    int batt = (treal >= 257) ? 1 : 0;
    int n0 = (treal - batt * 257) * 8;

    {
        float* sc4 = (float*)(smem + tb4 * 18944);   // [4][8][148]
        int w = tl >> 6, l = tl & 63;
        int lm = l & 15, quad = l >> 4;
        int qrow = n0 + (lm & 7);
        if (qrow > NN - 1) qrow = NN - 1;
        size_t qa = ((size_t)(batt * NN + qrow)) * HR + w * 32 + quad * 8;
        bf16x8 a0 = *(const bf16x8*)(q0 + qa);
        bf16x8 a1 = *(const bf16x8*)(q1 + qa);
        bf16x8 a2 = *(const bf16x8*)(q2 + qa);
        #pragma unroll
        for (int jt = 0; jt < 9; jt++) {
            int j = n0 - 64 + jt * 16 + lm;
            j = (j < 0) ? 0 : ((j > NN - 1) ? NN - 1 : j);
            size_t ka = ((size_t)(batt * NN + j)) * HR + w * 32 + quad * 8;
            bf16x8 kf0 = *(const bf16x8*)(k0 + ka);
            bf16x8 kf1 = *(const bf16x8*)(k1 + ka);
            bf16x8 kf2 = *(const bf16x8*)(k2 + ka);
            f32x4 acc = (f32x4)(0.f);
            acc = __builtin_amdgcn_mfma_f32_16x16x32_bf16(a0, kf0, acc, 0, 0, 0);
            acc = __builtin_amdgcn_mfma_f32_16x16x32_bf16(a0, kf1, acc, 0, 0, 0);
            acc = __builtin_amdgcn_mfma_f32_16x16x32_bf16(a1, kf0, acc, 0, 0, 0);
            acc = __builtin_amdgcn_mfma_f32_16x16x32_bf16(a1, kf1, acc, 0, 0, 0);
            acc = __builtin_amdgcn_mfma_f32_16x16x32_bf16(a0, kf2, acc, 0, 0, 0);
            acc = __builtin_amdgcn_mfma_f32_16x16x32_bf16(a2, kf0, acc, 0, 0, 0);
            if (quad < 2) {
                #pragma unroll
                for (int r = 0; r < 4; r++)
                    sc4[((size_t)w * 8 + quad * 4 + r) * 148 + jt * 16 + lm] = acc[r];
            }
        }
    }
    __syncthreads();

    {
        float* sc4  = (float*)(smem + tb4 * 18944);
        float* wgt2 = (float*)(smem + 75776 + tb4 * 6912);   // [144][12]
        int m = tl >> 5, p = tl & 31;
        int n = n0 + m;
        bool tokv = (n < NN);
        float sv[5]; bool vv[5];
        float mx = -INFINITY;
        #pragma unroll
        for (int i = 0; i < 5; i++) {
            int tap = p + 32 * i;
            bool inb = (tap < 144);
            int tapc = inb ? tap : 0;
            int j = n0 - 64 + tapc;
            float s0 = sc4[(0 * 8 + m) * 148 + tapc], s1 = sc4[(1 * 8 + m) * 148 + tapc];
            float s2 = sc4[(2 * 8 + m) * 148 + tapc], s3 = sc4[(3 * 8 + m) * 148 + tapc];
            float s = fmaxf(fmaxf(s0, s1), fmaxf(s2, s3)) * 0.17677669529663687f;
            bool v = inb && tokv && (tap >= m) && (tap <= m + 128) && (j >= 0) && (j < NN);
            sv[i] = s; vv[i] = v;
            if (v) mx = fmaxf(mx, fabsf(s));
        }
        for (int off = 16; off > 0; off >>= 1) mx = fmaxf(mx, __shfl_xor(mx, off, 64));
        float ee[5];
        float sum = 0.f;
        #pragma unroll
        for (int i = 0; i < 5; i++) {
            ee[i] = vv[i] ? expf(fabsf(sv[i]) - mx) : 0.f;
            sum += ee[i];
        }
        for (int off = 16; off > 0; off >>= 1) sum += __shfl_xor(sum, off, 64);
        float inv = (sum > 0.f) ? 1.f / sum : 0.f;
        float ds = 0.f;
        #pragma unroll
        for (int i = 0; i < 5; i++) {
            int tap = p + 32 * i;
            if (tap < 144) {
                float wg = vv[i] ? sgnf(sv[i]) * ee[i] * inv : 0.f;
                wgt2[tap * 12 + m] = wg;
                if (vv[i]) ds += wg * s_in[batt * NN + (n0 - 64 + tap)];
            }
        }
        for (int off = 16; off > 0; off >>= 1) ds += __shfl_xor(ds, off, 64);
        if (p == 0 && tokv && tile < NTILE) dstate_out[batt * NN + n] = ds;
    }
    __syncthreads();

    {
        float* wgt2 = (float*)(smem + 75776 + tb4 * 6912);
        float* redS = (float*)(smem + 131072 + tb4 * 256);
        float* redM = redS + 32;
        int w = tl >> 6, l = tl & 63;
        int d = (tl >> 2) * 4;
        int tg = tl & 3;
        int tok0 = tg * 2, tok1 = tg * 2 + 1;
        int jlo = (n0 >= 64) ? 0 : (64 - n0);
        int jhi = NN - 1 - n0 + 64; if (jhi > 135) jhi = 135;
        const float* vbase = valA + ((size_t)(batt * NN + n0 - 64)) * DD + d;
        f32x4 acc0 = (f32x4)(0.f), acc1 = (f32x4)(0.f);
        int jj = jlo;
        for (; jj + 3 <= jhi; jj += 4) {
            f32x4 v0 = *(const f32x4*)(vbase + (size_t)(jj + 0) * DD);
            f32x4 v1 = *(const f32x4*)(vbase + (size_t)(jj + 1) * DD);
            f32x4 v2 = *(const f32x4*)(vbase + (size_t)(jj + 2) * DD);
            f32x4 v3 = *(const f32x4*)(vbase + (size_t)(jj + 3) * DD);
            float wa0 = wgt2[(jj + 0) * 12 + tok0], wa1 = wgt2[(jj + 0) * 12 + tok1];
            float wb0 = wgt2[(jj + 1) * 12 + tok0], wb1 = wgt2[(jj + 1) * 12 + tok1];
            float wc0 = wgt2[(jj + 2) * 12 + tok0], wc1 = wgt2[(jj + 2) * 12 + tok1];
            float wd0 = wgt2[(jj + 3) * 12 + tok0], wd1 = wgt2[(jj + 3) * 12 + tok1];
            #pragma unroll
            for (int c = 0; c < 4; c++) {
                acc0[c] += v0[c] * wa0 + v1[c] * wb0 + v2[c] * wc0 + v3[c] * wd0;
                acc1[c] += v0[c] * wa1 + v1[c] * wb1 + v2[c] * wc1 + v3[c] * wd1;
            }
        }
        for (; jj <= jhi; jj++) {
            f32x4 v = *(const f32x4*)(vbase + (size_t)jj * DD);
            float w0 = wgt2[jj * 12 + tok0], w1 = wgt2[jj * 12 + tok1];
            #pragma unroll
            for (int c = 0; c < 4; c++) {
                acc0[c] += v[c] * w0;
                acc1[c] += v[c] * w1;
            }
        }
        f32x4 u[2]; f32x4 ac[2]; ac[0] = acc0; ac[1] = acc1;
        #pragma unroll
        for (int ti = 0; ti < 2; ti++) {
            int tok = tg * 2 + ti;
            int n = n0 + tok;
            f32x4 vold = (f32x4)(0.f);
            if (n < NN) vold = *(const f32x4*)(valA + ((size_t)(batt * NN + n)) * DD + d);
            u[ti] = vold + ac[ti];
            float s = u[ti][0]*u[ti][0] + u[ti][1]*u[ti][1] + u[ti][2]*u[ti][2] + u[ti][3]*u[ti][3];
            float mb = fmaxf(fmaxf(fabsf(ac[ti][0]), fabsf(ac[ti][1])),
                             fmaxf(fabsf(ac[ti][2]), fabsf(ac[ti][3])));
            for (int off = 4; off <= 32; off <<= 1) {
                s += __shfl_xor(s, off, 64);
                mb = fmaxf(mb, __shfl_xor(mb, off, 64));
            }
            if ((l >> 2) == 0) { redS[tok * 4 + w] = s; redM[tok * 4 + w] = mb; }
        }
        __syncthreads();
        #pragma unroll
        for (int ti = 0; ti < 2; ti++) {
            int tok = tg * 2 + ti;
            int slot = tb4 * 8 + tok;
            int n = n0 + tok;
            f32x4 o = (f32x4)(0.f);
            if (n < NN) {
                float ss = redS[tok * 4 + 0] + redS[tok * 4 + 1] + redS[tok * 4 + 2] + redS[tok * 4 + 3];
                float mab = fmaxf(fmaxf(redM[tok * 4 + 0], redM[tok * 4 + 1]),
                                  fmaxf(redM[tok * 4 + 2], redM[tok * 4 + 3]));
                float rn = 1.f / fmaxf(sqrtf(ss), EPSF);
                o = u[ti];
                if (mab > 0.f) { o[0] *= rn; o[1] *= rn; o[2] *= rn; o[3] *= rn; }
            }
            unsigned vbb = ((unsigned)(slot * 1024 + d * 4)) ^ ((unsigned)((slot & 7) << 4));
            *(f32x4*)(smem + vbb) = o;
            ushort4 hv, mv;
            {
                ushort h0 = f2b(o[0]); hv.x = h0; mv.x = f2b(o[0] - b2f(h0));
                ushort h1 = f2b(o[1]); hv.y = h1; mv.y = f2b(o[1] - b2f(h1));
                ushort h2 = f2b(o[2]); hv.z = h2; mv.z = f2b(o[2] - b2f(h2));
                ushort h3 = f2b(o[3]); hv.w = h3; mv.w = f2b(o[3] - b2f(h3));
            }
            unsigned pb = ((unsigned)(slot * 512 + d * 2)) ^ ((unsigned)((slot & 7) << 4));
            *(ushort4*)(smem + 32768 + pb) = hv;
            *(ushort4*)(smem + 49152 + pb) = mv;
        }
    }
    __syncthreads();

    // ---------------- ffn: two 16-slot groups ----------------
    int g   = t >> 9;
    int tg2 = t & 511;
    int w = tg2 >> 6, l = tg2 & 63;
    int lm = l & 15, quad = l >> 4;
    char* Hh_s = smem + 65536 + g * 16384;
    char* Hl_s = smem + 98304 + g * 16384;
    char* Y_s  = smem + 32768 + g * 16384;
    char* P_s  = smem + 65536 + g * 24576;

    // phase A: ffn1 + gelu + split -> H
    {
        int slot = g * 16 + lm;
        unsigned sxor = (unsigned)((slot & 7) << 4);
        unsigned vb0b = (unsigned)(slot * 512);
        f32x4 acc[4];
        #pragma unroll
        for (int jj = 0; jj < 4; jj++) acc[jj] = (f32x4)(0.f);
        #pragma unroll
        for (int kt = 0; kt < 8; kt++) {
            unsigned ab = (vb0b + kt * 64 + quad * 16) ^ sxor;
            bf16x8 ah = *(const bf16x8*)(smem + 32768 + ab);
            bf16x8 am = *(const bf16x8*)(smem + 49152 + ab);
            #pragma unroll
            for (int jj = 0; jj < 4; jj++) {
                int nt = w * 4 + jj;
                size_t off = ((size_t)(kt * 32 + nt) * 64 + l) * 8;
                bf16x8 bh = *(const bf16x8*)(W1h + off);
                bf16x8 bl = *(const bf16x8*)(W1l + off);
                acc[jj] = __builtin_amdgcn_mfma_f32_16x16x32_bf16(ah, bh, acc[jj], 0, 0, 0);
                acc[jj] = __builtin_amdgcn_mfma_f32_16x16x32_bf16(am, bh, acc[jj], 0, 0, 0);
                acc[jj] = __builtin_amdgcn_mfma_f32_16x16x32_bf16(ah, bl, acc[jj], 0, 0, 0);
            }
        }
        #pragma unroll
        for (int jj = 0; jj < 4; jj++) {
            int gn = (w * 4 + jj) * 16 + lm;
            float bb = b1[gn];
            #pragma unroll
            for (int r = 0; r < 4; r++) {
                int rho = quad * 4 + r;
                float x = acc[jj][r] + bb;
                float gl = 0.5f * x * (1.f + erff(x * 0.70710678118654752f));
                ushort gh = f2b(gl);
                unsigned byte = ((unsigned)(rho * 1024 + gn * 2)) ^
                                ((unsigned)((rho & 7) << 4));
                *(ushort*)(Hh_s + byte) = gh;
                *(ushort*)(Hl_s + byte) = f2b(gl - b2f(gh));
            }
        }
    }
    __syncthreads();

    // phase B: ffn2 + residual(valB LDS) -> Y
    {
        f32x4 acc[2];
        acc[0] = (f32x4)(0.f); acc[1] = (f32x4)(0.f);
        #pragma unroll
        for (int kt = 0; kt < 16; kt++) {
            unsigned ab = ((unsigned)(lm * 1024 + kt * 64 + quad * 16)) ^
                          ((unsigned)((lm & 7) << 4));
            bf16x8 ah = *(const bf16x8*)(Hh_s + ab);
            bf16x8 al = *(const bf16x8*)(Hl_s + ab);
            #pragma unroll
            for (int jj = 0; jj < 2; jj++) {
                int nt = w * 2 + jj;
                size_t off = ((size_t)(kt * 16 + nt) * 64 + l) * 8;
                bf16x8 bh = *(const bf16x8*)(W2h + off);
                bf16x8 bl = *(const bf16x8*)(W2l + off);
                acc[jj] = __builtin_amdgcn_mfma_f32_16x16x32_bf16(ah, bh, acc[jj], 0, 0, 0);
                acc[jj] = __builtin_amdgcn_mfma_f32_16x16x32_bf16(al, bh, acc[jj], 0, 0, 0);
                acc[jj] = __builtin_amdgcn_mfma_f32_16x16x32_bf16(ah, bl, acc[jj], 0, 0, 0);
            }
        }
        #pragma unroll
        for (int jj = 0; jj < 2; jj++) {
            int gn = (w * 2 + jj) * 16 + lm;
            float bb = b2[gn];
            #pragma unroll
            for (int r = 0; r < 4; r++) {
                int rho = quad * 4 + r;
                int slot = g * 16 + rho;
                unsigned rb = ((unsigned)(slot * 1024 + gn * 4)) ^
                              ((unsigned)((slot & 7) << 4));
                float y = *(const float*)(smem + rb) + acc[jj][r] + bb;
                unsigned byte = ((unsigned)(rho * 1024 + gn * 4)) ^
                                ((unsigned)((rho & 7) << 4));
                *(float*)(Y_s + byte) = y;
            }
        }
    }
    __syncthreads();

    // phase C
    if (last) {
        #pragma unroll
        for (int rr = 0; rr < 2; rr++) {
            int row = w * 2 + rr;
            int slot = g * 16 + row;
            int ts = 4 * bid + (slot >> 3);
            int tsc = (ts < NTILE) ? ts : (NTILE - 1);
            int bts = (tsc >= 257) ? 1 : 0;
            int n0s = (tsc - bts * 257) * 8;
            int nn = n0s + (slot & 7);
            bool vld = (ts < NTILE) && (nn < NN);
            unsigned byte = ((unsigned)(row * 1024 + l * 16)) ^
                            ((unsigned)((row & 7) << 4));
            f32x4 y = *(const f32x4*)(Y_s + byte);
            float s = y[0]*y[0] + y[1]*y[1] + y[2]*y[2] + y[3]*y[3];
            #pragma unroll
            for (int off = 1; off < 64; off <<= 1) s += __shfl_xor(s, off, 64);
            float rn = 1.f / fmaxf(sqrtf(s), EPSF);
            if (vld) {
                int grow = bts * NN + nn;
                f32x4 o;
                o[0] = y[0] * rn; o[1] = y[1] * rn; o[2] = y[2] * rn; o[3] = y[3] * rn;
                *(f32x4*)(out2 + (size_t)grow * DD + l * 4) = o;
            }
        }
        return;
    }

    #pragma unroll
    for (int rr = 0; rr < 2; rr++) {
        int row = w * 2 + rr;
        int slot = g * 16 + row;
        int ts = 4 * bid + (slot >> 3);
        int tsc = (ts < NTILE) ? ts : (NTILE - 1);
        int bts = (tsc >= 257) ? 1 : 0;
        int n0s = (tsc - bts * 257) * 8;
        int nn = n0s + (slot & 7);
        bool vld = (ts < NTILE) && (nn < NN);
        unsigned ybyte = ((unsigned)(row * 1024 + l * 16)) ^
                         ((unsigned)((row & 7) << 4));
        f32x4 x = *(const f32x4*)(Y_s + ybyte);
        float s = x[0]*x[0] + x[1]*x[1] + x[2]*x[2] + x[3]*x[3];
        #pragma unroll
        for (int off = 1; off < 64; off <<= 1) s += __shfl_xor(s, off, 64);
        float rn = 1.f / fmaxf(sqrtf(s), EPSF);
        x[0] *= rn; x[1] *= rn; x[2] *= rn; x[3] *= rn;
        if (vld) {
            int grow = bts * NN + nn;
            *(f32x4*)(valA_out + (size_t)grow * DD + l * 4) = x;
        }
        ushort4 h4, m4, l4;
        ushort hh, mm, ll;
        split3(x[0], hh, mm, ll); h4.x = hh; m4.x = mm; l4.x = ll;
        split3(x[1], hh, mm, ll); h4.y = hh; m4.y = mm; l4.y = ll;
        split3(x[2], hh, mm, ll); h4.z = hh; m4.z = mm; l4.z = ll;
        split3(x[3], hh, mm, ll); h4.w = hh; m4.w = mm; l4.w = ll;
        unsigned pbyte = ((unsigned)(row * 512 + l * 8)) ^ ((unsigned)((row & 7) << 4));
        *(ushort4*)(P_s + 0 * 8192 + pbyte) = h4;
        *(ushort4*)(P_s + 1 * 8192 + pbyte) = m4;
        *(ushort4*)(P_s + 2 * 8192 + pbyte) = l4;
    }
    __syncthreads();

    // q and k interleaved in one kt loop (per-acc order unchanged)
    {
        f32x4 aq = (f32x4)(0.f), ak = (f32x4)(0.f);
        #pragma unroll
        for (int kt = 0; kt < 8; kt++) {
            unsigned abyte = ((unsigned)(lm * 512 + kt * 64 + quad * 16)) ^
                             ((unsigned)((lm & 7) << 4));
            bf16x8 a0 = *(const bf16x8*)(P_s + 0 * 8192 + abyte);
            bf16x8 a1 = *(const bf16x8*)(P_s + 1 * 8192 + abyte);
            bf16x8 a2 = *(const bf16x8*)(P_s + 2 * 8192 + abyte);
            size_t off = ((size_t)(kt * 8 + w) * 64 + l) * 8;
            bf16x8 u0 = *(const bf16x8*)(U0 + off);
            bf16x8 u1 = *(const bf16x8*)(U1 + off);
            bf16x8 u2 = *(const bf16x8*)(U2 + off);
            bf16x8 v0 = *(const bf16x8*)(V0 + off);
            bf16x8 v1 = *(const bf16x8*)(V1 + off);
            bf16x8 v2 = *(const bf16x8*)(V2 + off);
            aq = __builtin_amdgcn_mfma_f32_16x16x32_bf16(a0, u0, aq, 0, 0, 0);
            ak = __builtin_amdgcn_mfma_f32_16x16x32_bf16(a0, v0, ak, 0, 0, 0);
            aq = __builtin_amdgcn_mfma_f32_16x16x32_bf16(a0, u1, aq, 0, 0, 0);
            ak = __builtin_amdgcn_mfma_f32_16x16x32_bf16(a0, v1, ak, 0, 0, 0);
            aq = __builtin_amdgcn_mfma_f32_16x16x32_bf16(a1, u0, aq, 0, 0, 0);
            ak = __builtin_amdgcn_mfma_f32_16x16x32_bf16(a1, v0, ak, 0, 0, 0);
            aq = __builtin_amdgcn_mfma_f32_16x16x32_bf16(a1, u1, aq, 0, 0, 0);
            ak = __builtin_amdgcn_mfma_f32_16x16x32_bf16(a1, v1, ak, 0, 0, 0);
            aq = __builtin_amdgcn_mfma_f32_16x16x32_bf16(a0, u2, aq, 0, 0, 0);
            ak = __builtin_amdgcn_mfma_f32_16x16x32_bf16(a0, v2, ak, 0, 0, 0);
            aq = __builtin_amdgcn_mfma_f32_16x16x32_bf16(a2, u0, aq, 0, 0, 0);
            ak = __builtin_amdgcn_mfma_f32_16x16x32_bf16(a2, v0, ak, 0, 0, 0);
        }
        int n = w * 16 + lm;
        #pragma unroll
        for (int r = 0; r < 4; r++) {
            int slot = g * 16 + quad * 4 + r;
            int ts = 4 * bid + (slot >> 3);
            int tsc = (ts < NTILE) ? ts : (NTILE - 1);
            int bts = (tsc >= 257) ? 1 : 0;
            int n0s = (tsc - bts * 257) * 8;
            int nn = n0s + (slot & 7);
            bool vld = (ts < NTILE) && (nn < NN);
            if (vld) {
                int grow = bts * NN + nn;
                ushort h, m, lo;
                size_t oi = (size_t)grow * HR + n;
                split3(aq[r], h, m, lo);
                oq0[oi] = h; oq1[oi] = m; oq2[oi] = lo;
                split3(ak[r], h, m, lo);
                ok0[oi] = h; ok1[oi] = m; ok2[oi] = lo;
            }
        }
    }
}

// =================== launcher ===================

extern "C" void kernel_launch(void* const* d_in, const int* in_sizes, int n_in,
                              void* d_out, int out_size, void* d_ws, size_t ws_size,
                              hipStream_t stream) {
    const int*   ids          = (const int*)d_in[0];
    const float* emb          = (const float*)d_in[1];
    const float* pos          = (const float*)d_in[2];
    const float* anchor_val   = (const float*)d_in[3];
    const float* anchor_state = (const float*)d_in[4];
    const float* Ws           = (const float*)d_in[5];
    const float* bs           = (const float*)d_in[6];
    const float* U            = (const float*)d_in[7];
    const float* V            = (const float*)d_in[8];
    const float* W1           = (const float*)d_in[9];
    const float* b1           = (const float*)d_in[10];
    const float* W2           = (const float*)d_in[11];
    const float* b2           = (const float*)d_in[12];
    float* out = (float*)d_out;

    ushort* p = (ushort*)d_ws;
    ushort* qkA = p; p += (size_t)6 * MM * HR;   // set0
    ushort* qkB = p; p += (size_t)6 * MM * HR;   // set1
    ushort* W1ph = p; p += 3 * 131072;
    ushort* W1pl = p; p += 3 * 131072;
    ushort* W2ph = p; p += 3 * 131072;
    ushort* W2pl = p; p += 3 * 131072;
    ushort* U0p = p; p += 3 * 32768;
    ushort* U1p = p; p += 3 * 32768;
    ushort* U2p = p; p += 3 * 32768;
    ushort* V0p = p; p += 3 * 32768;
    ushort* V1p = p; p += 3 * 32768;
    ushort* V2p = p; p += 3 * 32768;
    float* f = (float*)p;
    float* valA0 = f; f += (size_t)MM * DD;
    float* valA1 = f; f += (size_t)MM * DD;
    float* st0  = f; f += MM;
    float* st1  = f; f += MM;
    float* dst  = f; f += MM;

    ushort* S0[6], *S1[6];
    for (int i = 0; i < 6; i++) {
        S0[i] = qkA + (size_t)i * MM * HR;
        S1[i] = qkB + (size_t)i * MM * HR;
    }

    pre_kernel<<<EMB_BLKS + 960, 256, 0, stream>>>(ids, emb, pos, anchor_val, anchor_state,
                                                   Ws, bs, valA0, st0,
                                                   W1, W2, U, V,
                                                   W1ph, W1pl, W2ph, W2pl,
                                                   U0p, U1p, U2p, V0p, V1p, V2p);
    proj_kernel<<<dim3(257, 2), 256, 0, stream>>>(
        valA0, U0p, U1p, U2p, V0p, V1p, V2p,
        S0[0], S0[1], S0[2], S0[3], S0[4], S0[5]);

    float* s_in = st0;
    float* s_out = st1;
    for (int l = 0; l < 3; l++) {
        int par = l & 1;
        float* vin  = par ? valA1 : valA0;
        float* vout = par ? valA0 : valA1;
        ushort** qin  = par ? S1 : S0;
        ushort** qout = par ? S0 : S1;
        int ln = (l < 2) ? (l + 1) : 0;   // next layer's U/V (unused when last)
        layer_kernel<<<MBLK, 1024, 0, stream>>>(
            vin, s_in,
            qin[0], qin[1], qin[2], qin[3], qin[4], qin[5],
            W1ph + (size_t)l * 131072, W1pl + (size_t)l * 131072, b1 + (size_t)l * DFF,
            W2ph + (size_t)l * 131072, W2pl + (size_t)l * 131072, b2 + (size_t)l * DD,
            U0p + (size_t)ln * 32768, U1p + (size_t)ln * 32768, U2p + (size_t)ln * 32768,
            V0p + (size_t)ln * 32768, V1p + (size_t)ln * 32768, V2p + (size_t)ln * 32768,
            qout[0], qout[1], qout[2], qout[3], qout[4], qout[5],
            vout, dst,
            out + MM, (l == 2) ? 1 : 0);
        state_kernel<<<BB, 256, 0, stream>>>(s_in, dst, (l == 2) ? out : s_out);
        float* tmp = s_in; s_in = s_out; s_out = tmp;
    }
}

// Round 12
// 298.241 us; speedup vs baseline: 1.0519x; 1.0519x over previous
//
#include <hip/hip_runtime.h>
#include <hip/hip_bf16.h>
#include <math.h>

#define BB 2
#define SS 2048
#define NN 2049
#define MM (BB*NN)      // 4098 rows
#define DD 256
#define HR 128          // HEADS*RANK
#define NHEAD 4
#define DFF 512
#define EPSF 1e-6f
#define TB8 257
#define EMB_BLKS 1025   // ceil(MM/4)

typedef __attribute__((ext_vector_type(8))) short bf16x8;
typedef __attribute__((ext_vector_type(4))) float f32x4;

// ---------- helpers ----------
__device__ __forceinline__ float wave_sum(float v) {
    v += __shfl_down(v, 32, 64); v += __shfl_down(v, 16, 64);
    v += __shfl_down(v, 8, 64);  v += __shfl_down(v, 4, 64);
    v += __shfl_down(v, 2, 64);  v += __shfl_down(v, 1, 64);
    return v;
}
__device__ __forceinline__ float wave_max(float v) {
    v = fmaxf(v, __shfl_down(v, 32, 64)); v = fmaxf(v, __shfl_down(v, 16, 64));
    v = fmaxf(v, __shfl_down(v, 8, 64));  v = fmaxf(v, __shfl_down(v, 4, 64));
    v = fmaxf(v, __shfl_down(v, 2, 64));  v = fmaxf(v, __shfl_down(v, 1, 64));
    return v;
}
__device__ __forceinline__ float sgnf(float x) {
    return (x > 0.f) ? 1.f : ((x < 0.f) ? -1.f : 0.f);
}
__device__ __forceinline__ ushort f2b(float x) {
    __hip_bfloat16 h = __float2bfloat16(x);
    return *(ushort*)&h;
}
__device__ __forceinline__ float b2f(ushort u) {
    unsigned int v = ((unsigned int)u) << 16;
    return *(float*)&v;
}
__device__ __forceinline__ void split3(float x, ushort& h, ushort& m, ushort& l) {
    h = f2b(x);
    float r1 = x - b2f(h);
    m = f2b(r1);
    l = f2b(r1 - b2f(m));
}
__device__ __forceinline__ void pack_map(int e, int N, int& k, int& n) {
    int j = e & 7;
    int l = (e >> 3) & 63;
    int c = e >> 9;
    int ntiles = N >> 4;
    int kt = c / ntiles, nt = c - kt * ntiles;
    k = kt * 32 + ((l >> 4) << 3) + j;
    n = nt * 16 + (l & 15);
}

// =================== phase bodies ===================

__device__ __forceinline__ void pack_job(int idx,
    const float* __restrict__ W1, const float* __restrict__ W2,
    const float* __restrict__ U,  const float* __restrict__ V,
    ushort* __restrict__ W1ph, ushort* __restrict__ W1pl,
    ushort* __restrict__ W2ph, ushort* __restrict__ W2pl,
    ushort* __restrict__ U0, ushort* __restrict__ U1, ushort* __restrict__ U2,
    ushort* __restrict__ V0, ushort* __restrict__ V1, ushort* __restrict__ V2)
{
    int l = idx / 327680;
    int r = idx - l * 327680;
    if (l >= 3) return;
    int k, n;
    if (r < 131072) {
        int e = r;
        pack_map(e, 512, k, n);
        float s = W1[(size_t)l * 131072 + (size_t)k * 512 + n];
        ushort h = f2b(s);
        W1ph[(size_t)l * 131072 + e] = h;
        W1pl[(size_t)l * 131072 + e] = f2b(s - b2f(h));
    } else if (r < 262144) {
        int e = r - 131072;
        pack_map(e, 256, k, n);
        float s = W2[(size_t)l * 131072 + (size_t)k * 256 + n];
        ushort h = f2b(s);
        W2ph[(size_t)l * 131072 + e] = h;
        W2pl[(size_t)l * 131072 + e] = f2b(s - b2f(h));
    } else if (r < 294912) {
        int e = r - 262144;
        pack_map(e, 128, k, n);
        ushort h, m, lo;
        split3(U[(size_t)l * 32768 + (size_t)k * 128 + n], h, m, lo);
        U0[(size_t)l * 32768 + e] = h;
        U1[(size_t)l * 32768 + e] = m;
        U2[(size_t)l * 32768 + e] = lo;
    } else {
        int e = r - 294912;
        pack_map(e, 128, k, n);
        ushort h, m, lo;
        split3(V[(size_t)l * 32768 + (size_t)k * 128 + n], h, m, lo);
        V0[(size_t)l * 32768 + e] = h;
        V1[(size_t)l * 32768 + e] = m;
        V2[(size_t)l * 32768 + e] = lo;
    }
}

__device__ __forceinline__ void state_job(int b, int t, float* red,
    const float* __restrict__ state_in, const float* __restrict__ dstate,
    float* __restrict__ state_out)
{
    float lmax = -INFINITY;
    for (int n = t; n < NN; n += 256) {
        float x = state_in[b * NN + n] + dstate[b * NN + n];
        lmax = fmaxf(lmax, fabsf(x));
    }
    lmax = wave_max(lmax);
    if ((t & 63) == 0) red[t >> 6] = lmax;
    __syncthreads();
    float m = fmaxf(fmaxf(red[0], red[1]), fmaxf(red[2], red[3]));
    float lsum = 0.f;
    for (int n = t; n < NN; n += 256)
        lsum += expf(fabsf(state_in[b * NN + n] + dstate[b * NN + n]) - m);
    lsum = wave_sum(lsum);
    __syncthreads();
    if ((t & 63) == 0) red[4 + (t >> 6)] = lsum;
    __syncthreads();
    float inv = 1.f / (red[4] + red[5] + red[6] + red[7]);
    for (int n = t; n < NN; n += 256) {
        float x = state_in[b * NN + n] + dstate[b * NN + n];
        state_out[b * NN + n] = sgnf(x) * expf(fabsf(x) - m) * inv;
    }
}

// =================== pre: embed (4 rows/block, wave-per-row) + weight pack (4 elem/thread) ===================

__global__ void pre_kernel(const int* __restrict__ ids, const float* __restrict__ emb,
                           const float* __restrict__ pos, const float* __restrict__ anchor_val,
                           const float* __restrict__ anchor_state, const float* __restrict__ Ws,
                           const float* __restrict__ bs, float* __restrict__ val,
                           float* __restrict__ state,
                           const float* __restrict__ W1, const float* __restrict__ W2,
                           const float* __restrict__ U,  const float* __restrict__ V,
                           ushort* W1ph, ushort* W1pl, ushort* W2ph, ushort* W2pl,
                           ushort* U0, ushort* U1, ushort* U2,
                           ushort* V0, ushort* V1, ushort* V2) {
    int bid = blockIdx.x;
    int t = threadIdx.x;
    if (bid < EMB_BLKS) {
        int w = t >> 6, l = t & 63;
        int row = bid * 4 + w;
        if (row >= MM) return;
        int b = row / NN, n = row % NN;
        f32x4 e;
        if (n == 0) {
            e = *(const f32x4*)(anchor_val + l * 4);
        } else {
            int id = ids[b * SS + (n - 1)];
            f32x4 em = *(const f32x4*)(emb + (size_t)id * DD + l * 4);
            f32x4 po = *(const f32x4*)(pos + (size_t)(n - 1) * DD + l * 4);
            e = em + po;
        }
        f32x4 wv = *(const f32x4*)(Ws + l * 4);
        float ss = e[0]*e[0] + e[1]*e[1] + e[2]*e[2] + e[3]*e[3];
        float ts = e[0]*wv[0] + e[1]*wv[1] + e[2]*wv[2] + e[3]*wv[3];
        #pragma unroll
        for (int off = 1; off < 64; off <<= 1) {
            ss += __shfl_xor(ss, off, 64);
            ts += __shfl_xor(ts, off, 64);
        }
        float rn = 1.f / fmaxf(sqrtf(ss), EPSF);
        f32x4 o;
        o[0] = e[0] * rn; o[1] = e[1] * rn; o[2] = e[2] * rn; o[3] = e[3] * rn;
        *(f32x4*)(val + (size_t)row * DD + l * 4) = o;
        if (l == 0) state[row] = (n == 0) ? anchor_state[0] : (ts + bs[0]);
        return;
    }
    int base = (bid - EMB_BLKS) * 1024 + t;
    #pragma unroll
    for (int k = 0; k < 4; k++)
        pack_job(base + k * 256, W1, W2, U, V,
                 W1ph, W1pl, W2ph, W2pl, U0, U1, U2, V0, V1, V2);
}

// =================== proj0: layer-0 q/k projection (input already unit rows) ===================

__global__ __launch_bounds__(256, 3)
void proj_kernel(const float* __restrict__ Xin,
                 const ushort* __restrict__ U0, const ushort* __restrict__ U1,
                 const ushort* __restrict__ U2,
                 const ushort* __restrict__ V0, const ushort* __restrict__ V1,
                 const ushort* __restrict__ V2,
                 ushort* __restrict__ q0, ushort* __restrict__ q1,
                 ushort* __restrict__ q2,
                 ushort* __restrict__ k0, ushort* __restrict__ k1,
                 ushort* __restrict__ k2) {
    __shared__ __align__(16) char smem[24576];   // 3 bf16 A-planes, XOR-swizzled
    int t = threadIdx.x;
    int w = t >> 6, l = t & 63;
    int lm = l & 15, quad = l >> 4;
    int m0 = blockIdx.x * 16;
    bool isQ = (blockIdx.y == 0);
    const ushort* P0 = isQ ? U0 : V0;
    const ushort* P1 = isQ ? U1 : V1;
    const ushort* P2 = isQ ? U2 : V2;

    #pragma unroll
    for (int rr = 0; rr < 4; rr++) {
        int row = w * 4 + rr;
        int tok = m0 + row; if (tok > MM - 1) tok = MM - 1;
        f32x4 x = *(const f32x4*)(Xin + (size_t)tok * DD + l * 4);
        ushort4 h4, m4, l4;
        ushort hh, mm, ll;
        split3(x[0], hh, mm, ll); h4.x = hh; m4.x = mm; l4.x = ll;
        split3(x[1], hh, mm, ll); h4.y = hh; m4.y = mm; l4.y = ll;
        split3(x[2], hh, mm, ll); h4.z = hh; m4.z = mm; l4.z = ll;
        split3(x[3], hh, mm, ll); h4.w = hh; m4.w = mm; l4.w = ll;
        unsigned byte = ((unsigned)(row * 512 + l * 8)) ^ ((unsigned)((row & 7) << 4));
        *(ushort4*)(smem + 0 * 8192 + byte) = h4;
        *(ushort4*)(smem + 1 * 8192 + byte) = m4;
        *(ushort4*)(smem + 2 * 8192 + byte) = l4;
    }
    __syncthreads();

    f32x4 acc[2];
    acc[0] = (f32x4)(0.f); acc[1] = (f32x4)(0.f);
    #pragma unroll
    for (int kt = 0; kt < 8; kt++) {
        unsigned abyte = ((unsigned)(lm * 512 + kt * 64 + quad * 16)) ^
                         ((unsigned)((lm & 7) << 4));
        bf16x8 a0 = *(const bf16x8*)(smem + 0 * 8192 + abyte);
        bf16x8 a1 = *(const bf16x8*)(smem + 1 * 8192 + abyte);
        bf16x8 a2 = *(const bf16x8*)(smem + 2 * 8192 + abyte);
        #pragma unroll
        for (int jj = 0; jj < 2; jj++) {
            int ntl = w * 2 + jj;
            size_t off = ((size_t)(kt * 8 + ntl) * 64 + l) * 8;
            bf16x8 b0 = *(const bf16x8*)(P0 + off);
            bf16x8 b1 = *(const bf16x8*)(P1 + off);
            bf16x8 b2 = *(const bf16x8*)(P2 + off);
            acc[jj] = __builtin_amdgcn_mfma_f32_16x16x32_bf16(a0, b0, acc[jj], 0, 0, 0);
            acc[jj] = __builtin_amdgcn_mfma_f32_16x16x32_bf16(a0, b1, acc[jj], 0, 0, 0);
            acc[jj] = __builtin_amdgcn_mfma_f32_16x16x32_bf16(a1, b0, acc[jj], 0, 0, 0);
            acc[jj] = __builtin_amdgcn_mfma_f32_16x16x32_bf16(a1, b1, acc[jj], 0, 0, 0);
            acc[jj] = __builtin_amdgcn_mfma_f32_16x16x32_bf16(a0, b2, acc[jj], 0, 0, 0);
            acc[jj] = __builtin_amdgcn_mfma_f32_16x16x32_bf16(a2, b0, acc[jj], 0, 0, 0);
        }
    }
    ushort* o0 = isQ ? q0 : k0;
    ushort* o1 = isQ ? q1 : k1;
    ushort* o2 = isQ ? q2 : k2;
    #pragma unroll
    for (int jj = 0; jj < 2; jj++) {
        int n = (w * 2 + jj) * 16 + lm;
        #pragma unroll
        for (int r = 0; r < 4; r++) {
            int tok = m0 + quad * 4 + r;
            if (tok < MM) {
                ushort h, m, lo;
                split3(acc[jj][r], h, m, lo);
                size_t oi = (size_t)tok * HR + n;
                o0[oi] = h; o1[oi] = m; o2[oi] = lo;
            }
        }
    }
}

// =================== attention (unchanged body) ===================

__global__ __launch_bounds__(256, 3)
void attn_kernel(const float* __restrict__ val_in,
                 const float* __restrict__ state_in,
                 const ushort* __restrict__ q0, const ushort* __restrict__ q1,
                 const ushort* __restrict__ q2,
                 const ushort* __restrict__ k0, const ushort* __restrict__ k1,
                 const ushort* __restrict__ k2,
                 float* __restrict__ val_out,
                 ushort* __restrict__ vbH, ushort* __restrict__ vbM,
                 float* __restrict__ dstate_out) {
    __shared__ float sc4[NHEAD][8][148];
    __shared__ float wgt2[144][12];
    __shared__ float redS[8][4];
    __shared__ float redM[8][4];

    int b = blockIdx.x / TB8;
    int n0 = (blockIdx.x % TB8) * 8;
    int t = threadIdx.x;
    int w = t >> 6, l = t & 63;
    int lm = l & 15, quad = l >> 4;

    {
        int qrow = n0 + (lm & 7);
        if (qrow > NN - 1) qrow = NN - 1;
        size_t qa = ((size_t)(b * NN + qrow)) * HR + w * 32 + quad * 8;
        bf16x8 a0 = *(const bf16x8*)(q0 + qa);
        bf16x8 a1 = *(const bf16x8*)(q1 + qa);
        bf16x8 a2 = *(const bf16x8*)(q2 + qa);
        #pragma unroll
        for (int jt = 0; jt < 9; jt++) {
            int j = n0 - 64 + jt * 16 + lm;
            j = (j < 0) ? 0 : ((j > NN - 1) ? NN - 1 : j);
            size_t ka = ((size_t)(b * NN + j)) * HR + w * 32 + quad * 8;
            bf16x8 kf0 = *(const bf16x8*)(k0 + ka);
            bf16x8 kf1 = *(const bf16x8*)(k1 + ka);
            bf16x8 kf2 = *(const bf16x8*)(k2 + ka);
            f32x4 acc = (f32x4)(0.f);
            acc = __builtin_amdgcn_mfma_f32_16x16x32_bf16(a0, kf0, acc, 0, 0, 0);
            acc = __builtin_amdgcn_mfma_f32_16x16x32_bf16(a0, kf1, acc, 0, 0, 0);
            acc = __builtin_amdgcn_mfma_f32_16x16x32_bf16(a1, kf0, acc, 0, 0, 0);
            acc = __builtin_amdgcn_mfma_f32_16x16x32_bf16(a1, kf1, acc, 0, 0, 0);
            acc = __builtin_amdgcn_mfma_f32_16x16x32_bf16(a0, kf2, acc, 0, 0, 0);
            acc = __builtin_amdgcn_mfma_f32_16x16x32_bf16(a2, kf0, acc, 0, 0, 0);
            if (quad < 2) {
                #pragma unroll
                for (int r = 0; r < 4; r++)
                    sc4[w][quad * 4 + r][jt * 16 + lm] = acc[r];
            }
        }
    }
    __syncthreads();

    {
        int m = t >> 5, p = t & 31;
        int n = n0 + m;
        bool tokv = (n < NN);
        float sv[5]; bool vv[5];
        float mx = -INFINITY;
        #pragma unroll
        for (int i = 0; i < 5; i++) {
            int tap = p + 32 * i;
            bool inb = (tap < 144);
            int tapc = inb ? tap : 0;
            int j = n0 - 64 + tapc;
            float s0 = sc4[0][m][tapc], s1 = sc4[1][m][tapc];
            float s2 = sc4[2][m][tapc], s3 = sc4[3][m][tapc];
            float s = fmaxf(fmaxf(s0, s1), fmaxf(s2, s3)) * 0.17677669529663687f;
            bool v = inb && tokv && (tap >= m) && (tap <= m + 128) && (j >= 0) && (j < NN);
            sv[i] = s; vv[i] = v;
            if (v) mx = fmaxf(mx, fabsf(s));
        }
        for (int off = 16; off > 0; off >>= 1) mx = fmaxf(mx, __shfl_xor(mx, off, 64));
        float ee[5];
        float sum = 0.f;
        #pragma unroll
        for (int i = 0; i < 5; i++) {
            ee[i] = vv[i] ? expf(fabsf(sv[i]) - mx) : 0.f;
            sum += ee[i];
        }
        for (int off = 16; off > 0; off >>= 1) sum += __shfl_xor(sum, off, 64);
        float inv = (sum > 0.f) ? 1.f / sum : 0.f;
        float ds = 0.f;
        #pragma unroll
        for (int i = 0; i < 5; i++) {
            int tap = p + 32 * i;
            if (tap < 144) {
                float wg = vv[i] ? sgnf(sv[i]) * ee[i] * inv : 0.f;
                wgt2[tap][m] = wg;
                if (vv[i]) ds += wg * state_in[b * NN + (n0 - 64 + tap)];
            }
        }
        for (int off = 16; off > 0; off >>= 1) ds += __shfl_xor(ds, off, 64);
        if (p == 0 && tokv) dstate_out[b * NN + n] = ds;
    }
    __syncthreads();

    {
        int d = (t >> 2) * 4;
        int tg = t & 3;
        int tok0 = tg * 2, tok1 = tg * 2 + 1;
        int jlo = (n0 >= 64) ? 0 : (64 - n0);
        int jhi = NN - 1 - n0 + 64; if (jhi > 135) jhi = 135;
        const float* vbase = val_in + ((size_t)(b * NN + n0 - 64)) * DD + d;
        f32x4 acc0 = (f32x4)(0.f), acc1 = (f32x4)(0.f);
        int jj = jlo;
        for (; jj + 3 <= jhi; jj += 4) {
            f32x4 v0 = *(const f32x4*)(vbase + (size_t)(jj + 0) * DD);
            f32x4 v1 = *(const f32x4*)(vbase + (size_t)(jj + 1) * DD);
            f32x4 v2 = *(const f32x4*)(vbase + (size_t)(jj + 2) * DD);
            f32x4 v3 = *(const f32x4*)(vbase + (size_t)(jj + 3) * DD);
            float wa0 = wgt2[jj + 0][tok0], wa1 = wgt2[jj + 0][tok1];
            float wb0 = wgt2[jj + 1][tok0], wb1 = wgt2[jj + 1][tok1];
            float wc0 = wgt2[jj + 2][tok0], wc1 = wgt2[jj + 2][tok1];
            float wd0 = wgt2[jj + 3][tok0], wd1 = wgt2[jj + 3][tok1];
            #pragma unroll
            for (int c = 0; c < 4; c++) {
                acc0[c] += v0[c] * wa0 + v1[c] * wb0 + v2[c] * wc0 + v3[c] * wd0;
                acc1[c] += v0[c] * wa1 + v1[c] * wb1 + v2[c] * wc1 + v3[c] * wd1;
            }
        }
        for (; jj <= jhi; jj++) {
            f32x4 v = *(const f32x4*)(vbase + (size_t)jj * DD);
            float w0 = wgt2[jj][tok0], w1 = wgt2[jj][tok1];
            #pragma unroll
            for (int c = 0; c < 4; c++) {
                acc0[c] += v[c] * w0;
                acc1[c] += v[c] * w1;
            }
        }
        f32x4 u[2]; f32x4 ac[2]; ac[0] = acc0; ac[1] = acc1;
        #pragma unroll
        for (int ti = 0; ti < 2; ti++) {
            int tok = tg * 2 + ti;
            int n = n0 + tok;
            f32x4 vold = (f32x4)(0.f);
            if (n < NN) vold = *(const f32x4*)(val_in + ((size_t)(b * NN + n)) * DD + d);
            u[ti] = vold + ac[ti];
            float s = u[ti][0]*u[ti][0] + u[ti][1]*u[ti][1] + u[ti][2]*u[ti][2] + u[ti][3]*u[ti][3];
            float mb = fmaxf(fmaxf(fabsf(ac[ti][0]), fabsf(ac[ti][1])),
                             fmaxf(fabsf(ac[ti][2]), fabsf(ac[ti][3])));
            for (int off = 4; off <= 32; off <<= 1) {
                s += __shfl_xor(s, off, 64);
                mb = fmaxf(mb, __shfl_xor(mb, off, 64));
            }
            if ((l >> 2) == 0) { redS[tok][w] = s; redM[tok][w] = mb; }
        }
        __syncthreads();
        #pragma unroll
        for (int ti = 0; ti < 2; ti++) {
            int tok = tg * 2 + ti;
            int n = n0 + tok;
            if (n < NN) {
                float ss = redS[tok][0] + redS[tok][1] + redS[tok][2] + redS[tok][3];
                float mab = fmaxf(fmaxf(redM[tok][0], redM[tok][1]),
                                  fmaxf(redM[tok][2], redM[tok][3]));
                float rn = 1.f / fmaxf(sqrtf(ss), EPSF);
                f32x4 o = u[ti];
                if (mab > 0.f) { o[0] *= rn; o[1] *= rn; o[2] *= rn; o[3] *= rn; }
                size_t oi = ((size_t)(b * NN + n)) * DD + d;
                *(f32x4*)(val_out + oi) = o;
                ushort4 hv, mv;
                {
                    ushort h0 = f2b(o[0]); hv.x = h0; mv.x = f2b(o[0] - b2f(h0));
                    ushort h1 = f2b(o[1]); hv.y = h1; mv.y = f2b(o[1] - b2f(h1));
                    ushort h2 = f2b(o[2]); hv.z = h2; mv.z = f2b(o[2] - b2f(h2));
                    ushort h3 = f2b(o[3]); hv.w = h3; mv.w = f2b(o[3] - b2f(h3));
                }
                *(ushort4*)(vbH + oi) = hv;
                *(ushort4*)(vbM + oi) = mv;
            }
        }
    }
}

// =================== fused F (1024 threads / 16 waves, 32-row strips):
//   two 8-wave tile-groups, each = one 16-row M-tile.
//   Blocks 0..127: rows bid*32..+31. Block 128: rows 4096..4097 (clamped tiles).
//   Blocks 129,130: state signed-softmax.
// LDS: Hh[2][16K] @0 | Hl[2][16K] @32K | Y[2][16K] @64K ; phase C aliases
//   A-planes[2][24K] over [0,48K) (H dead by then).

__global__ __launch_bounds__(1024, 1)
void fusedF_kernel(const ushort* __restrict__ vb0, const ushort* __restrict__ vb1,
                   const float*  __restrict__ valB,
                   const ushort* __restrict__ W1h, const ushort* __restrict__ W1l,
                   const float*  __restrict__ b1,
                   const ushort* __restrict__ W2h, const ushort* __restrict__ W2l,
                   const float*  __restrict__ b2,
                   const ushort* __restrict__ U0, const ushort* __restrict__ U1,
                   const ushort* __restrict__ U2,
                   const ushort* __restrict__ V0, const ushort* __restrict__ V1,
                   const ushort* __restrict__ V2,
                   ushort* __restrict__ q0, ushort* __restrict__ q1,
                   ushort* __restrict__ q2,
                   ushort* __restrict__ k0, ushort* __restrict__ k1,
                   ushort* __restrict__ k2,
                   float* __restrict__ valA,
                   const float* __restrict__ s_in, const float* __restrict__ dstate,
                   float* __restrict__ s_out,
                   float* __restrict__ out2, int last)
{
    __shared__ __align__(16) char smem[98304];
    int t = threadIdx.x;
    int bid = blockIdx.x;

    if (bid >= 129) {
        if (bid - 129 < BB) {
            if (t < 256) {
                state_job(bid - 129, t, (float*)smem, s_in, dstate, s_out);
            } else {
                __syncthreads(); __syncthreads(); __syncthreads();
            }
        }
        return;
    }

    int g  = t >> 9;                 // tile group 0/1
    int tl = t & 511;
    int w = tl >> 6, l = tl & 63;    // w in 0..7 within group
    int lm = l & 15, quad = l >> 4;
    int m0 = bid * 32 + g * 16;
    int row0 = m0 + lm; if (row0 > MM - 1) row0 = MM - 1;
    char* Hh_s = smem + g * 16384;
    char* Hl_s = smem + 32768 + g * 16384;
    char* Y_s  = smem + 65536 + g * 16384;
    char* P_s  = smem + g * 24576;   // phase C A-planes (alias over H region)

    // ---- phase A: ffn1 (512 cols across 8 waves/group), gelu, split -> H in LDS ----
    {
        const ushort* xh = vb0 + (size_t)row0 * DD + quad * 8;
        const ushort* xm = vb1 + (size_t)row0 * DD + quad * 8;
        f32x4 acc[4];
        #pragma unroll
        for (int jj = 0; jj < 4; jj++) acc[jj] = (f32x4)(0.f);
        #pragma unroll
        for (int kt = 0; kt < 8; kt++) {
            bf16x8 ah = *(const bf16x8*)(xh + kt * 32);
            bf16x8 am = *(const bf16x8*)(xm + kt * 32);
            #pragma unroll
            for (int jj = 0; jj < 4; jj++) {
                int nt = w * 4 + jj;
                size_t off = ((size_t)(kt * 32 + nt) * 64 + l) * 8;
                bf16x8 bh = *(const bf16x8*)(W1h + off);
                bf16x8 bl = *(const bf16x8*)(W1l + off);
                acc[jj] = __builtin_amdgcn_mfma_f32_16x16x32_bf16(ah, bh, acc[jj], 0, 0, 0);
                acc[jj] = __builtin_amdgcn_mfma_f32_16x16x32_bf16(am, bh, acc[jj], 0, 0, 0);
                acc[jj] = __builtin_amdgcn_mfma_f32_16x16x32_bf16(ah, bl, acc[jj], 0, 0, 0);
            }
        }
        #pragma unroll
        for (int jj = 0; jj < 4; jj++) {
            int gn = (w * 4 + jj) * 16 + lm;
            float bb = b1[gn];
            #pragma unroll
            for (int r = 0; r < 4; r++) {
                int rho = quad * 4 + r;
                float x = acc[jj][r] + bb;
                float gl = 0.5f * x * (1.f + erff(x * 0.70710678118654752f));
                ushort gh = f2b(gl);
                unsigned byte = ((unsigned)(rho * 1024 + gn * 2)) ^
                                ((unsigned)((rho & 7) << 4));
                *(ushort*)(Hh_s + byte) = gh;
                *(ushort*)(Hl_s + byte) = f2b(gl - b2f(gh));
            }
        }
    }
    __syncthreads();

    // ---- phase B: ffn2 from LDS H -> Y (f32) in LDS ----
    {
        f32x4 acc[2];
        acc[0] = (f32x4)(0.f); acc[1] = (f32x4)(0.f);
        #pragma unroll
        for (int kt = 0; kt < 16; kt++) {
            unsigned ab = ((unsigned)(lm * 1024 + kt * 64 + quad * 16)) ^
                          ((unsigned)((lm & 7) << 4));
            bf16x8 ah = *(const bf16x8*)(Hh_s + ab);
            bf16x8 al = *(const bf16x8*)(Hl_s + ab);
            #pragma unroll
            for (int jj = 0; jj < 2; jj++) {
                int nt = w * 2 + jj;
                size_t off = ((size_t)(kt * 16 + nt) * 64 + l) * 8;
                bf16x8 bh = *(const bf16x8*)(W2h + off);
                bf16x8 bl = *(const bf16x8*)(W2l + off);
                acc[jj] = __builtin_amdgcn_mfma_f32_16x16x32_bf16(ah, bh, acc[jj], 0, 0, 0);
                acc[jj] = __builtin_amdgcn_mfma_f32_16x16x32_bf16(al, bh, acc[jj], 0, 0, 0);
                acc[jj] = __builtin_amdgcn_mfma_f32_16x16x32_bf16(ah, bl, acc[jj], 0, 0, 0);
            }
        }
        #pragma unroll
        for (int jj = 0; jj < 2; jj++) {
            int gn = (w * 2 + jj) * 16 + lm;
            float bb = b2[gn];
            #pragma unroll
            for (int r = 0; r < 4; r++) {
                int rho = quad * 4 + r;
                int tok = m0 + rho;
                int tokc = (tok > MM - 1) ? (MM - 1) : tok;
                float y = valB[(size_t)tokc * DD + gn] + acc[jj][r] + bb;
                unsigned byte = ((unsigned)(rho * 1024 + gn * 4)) ^
                                ((unsigned)((rho & 7) << 4));
                *(float*)(Y_s + byte) = y;
            }
        }
    }
    __syncthreads();

    // ---- phase C ----
    if (last) {
        #pragma unroll
        for (int rr = 0; rr < 2; rr++) {
            int row = w * 2 + rr;
            int tok = m0 + row;
            unsigned byte = ((unsigned)(row * 1024 + l * 16)) ^
                            ((unsigned)((row & 7) << 4));
            f32x4 y = *(const f32x4*)(Y_s + byte);
            float s = y[0]*y[0] + y[1]*y[1] + y[2]*y[2] + y[3]*y[3];
            #pragma unroll
            for (int off = 1; off < 64; off <<= 1) s += __shfl_xor(s, off, 64);
            float rn = 1.f / fmaxf(sqrtf(s), EPSF);
            if (tok < MM) {
                f32x4 o;
                o[0] = y[0] * rn; o[1] = y[1] * rn; o[2] = y[2] * rn; o[3] = y[3] * rn;
                *(f32x4*)(out2 + (size_t)tok * DD + l * 4) = o;
            }
        }
        return;
    }

    // next-layer input: norm rows, write valA, split3 -> A-planes (alias over H)
    #pragma unroll
    for (int rr = 0; rr < 2; rr++) {
        int row = w * 2 + rr;
        int tok = m0 + row;
        unsigned ybyte = ((unsigned)(row * 1024 + l * 16)) ^
                         ((unsigned)((row & 7) << 4));
        f32x4 x = *(const f32x4*)(Y_s + ybyte);
        float s = x[0]*x[0] + x[1]*x[1] + x[2]*x[2] + x[3]*x[3];
        #pragma unroll
        for (int off = 1; off < 64; off <<= 1) s += __shfl_xor(s, off, 64);
        float rn = 1.f / fmaxf(sqrtf(s), EPSF);
        x[0] *= rn; x[1] *= rn; x[2] *= rn; x[3] *= rn;
        if (tok < MM) *(f32x4*)(valA + (size_t)tok * DD + l * 4) = x;
        ushort4 h4, m4, l4;
        ushort hh, mm, ll;
        split3(x[0], hh, mm, ll); h4.x = hh; m4.x = mm; l4.x = ll;
        split3(x[1], hh, mm, ll); h4.y = hh; m4.y = mm; l4.y = ll;
        split3(x[2], hh, mm, ll); h4.z = hh; m4.z = mm; l4.z = ll;
        split3(x[3], hh, mm, ll); h4.w = hh; m4.w = mm; l4.w = ll;
        unsigned pbyte = ((unsigned)(row * 512 + l * 8)) ^ ((unsigned)((row & 7) << 4));
        *(ushort4*)(P_s + 0 * 8192 + pbyte) = h4;
        *(ushort4*)(P_s + 1 * 8192 + pbyte) = m4;
        *(ushort4*)(P_s + 2 * 8192 + pbyte) = l4;
    }
    __syncthreads();

    // q and k interleaved in ONE kt loop (halves the serial chain; per-acc
    // MFMA order unchanged -> bit-identical results)
    {
        f32x4 aq = (f32x4)(0.f), ak = (f32x4)(0.f);
        #pragma unroll
        for (int kt = 0; kt < 8; kt++) {
            unsigned abyte = ((unsigned)(lm * 512 + kt * 64 + quad * 16)) ^
                             ((unsigned)((lm & 7) << 4));
            bf16x8 a0 = *(const bf16x8*)(P_s + 0 * 8192 + abyte);
            bf16x8 a1 = *(const bf16x8*)(P_s + 1 * 8192 + abyte);
            bf16x8 a2 = *(const bf16x8*)(P_s + 2 * 8192 + abyte);
            size_t off = ((size_t)(kt * 8 + w) * 64 + l) * 8;
            bf16x8 u0 = *(const bf16x8*)(U0 + off);
            bf16x8 u1 = *(const bf16x8*)(U1 + off);
            bf16x8 u2 = *(const bf16x8*)(U2 + off);
            bf16x8 v0 = *(const bf16x8*)(V0 + off);
            bf16x8 v1 = *(const bf16x8*)(V1 + off);
            bf16x8 v2 = *(const bf16x8*)(V2 + off);
            aq = __builtin_amdgcn_mfma_f32_16x16x32_bf16(a0, u0, aq, 0, 0, 0);
            ak = __builtin_amdgcn_mfma_f32_16x16x32_bf16(a0, v0, ak, 0, 0, 0);
            aq = __builtin_amdgcn_mfma_f32_16x16x32_bf16(a0, u1, aq, 0, 0, 0);
            ak = __builtin_amdgcn_mfma_f32_16x16x32_bf16(a0, v1, ak, 0, 0, 0);
            aq = __builtin_amdgcn_mfma_f32_16x16x32_bf16(a1, u0, aq, 0, 0, 0);
            ak = __builtin_amdgcn_mfma_f32_16x16x32_bf16(a1, v0, ak, 0, 0, 0);
            aq = __builtin_amdgcn_mfma_f32_16x16x32_bf16(a1, u1, aq, 0, 0, 0);
            ak = __builtin_amdgcn_mfma_f32_16x16x32_bf16(a1, v1, ak, 0, 0, 0);
            aq = __builtin_amdgcn_mfma_f32_16x16x32_bf16(a0, u2, aq, 0, 0, 0);
            ak = __builtin_amdgcn_mfma_f32_16x16x32_bf16(a0, v2, ak, 0, 0, 0);
            aq = __builtin_amdgcn_mfma_f32_16x16x32_bf16(a2, u0, aq, 0, 0, 0);
            ak = __builtin_amdgcn_mfma_f32_16x16x32_bf16(a2, v0, ak, 0, 0, 0);
        }
        int n = w * 16 + lm;
        #pragma unroll
        for (int r = 0; r < 4; r++) {
            int tok = m0 + quad * 4 + r;
            if (tok < MM) {
                ushort h, m, lo;
                size_t oi = (size_t)tok * HR + n;
                split3(aq[r], h, m, lo);
                q0[oi] = h; q1[oi] = m; q2[oi] = lo;
                split3(ak[r], h, m, lo);
                k0[oi] = h; k1[oi] = m; k2[oi] = lo;
            }
        }
    }
}

// =================== launcher ===================

extern "C" void kernel_launch(void* const* d_in, const int* in_sizes, int n_in,
                              void* d_out, int out_size, void* d_ws, size_t ws_size,
                              hipStream_t stream) {
    const int*   ids          = (const int*)d_in[0];
    const float* emb          = (const float*)d_in[1];
    const float* pos          = (const float*)d_in[2];
    const float* anchor_val   = (const float*)d_in[3];
    const float* anchor_state = (const float*)d_in[4];
    const float* Ws           = (const float*)d_in[5];
    const float* bs           = (const float*)d_in[6];
    const float* U            = (const float*)d_in[7];
    const float* V            = (const float*)d_in[8];
    const float* W1           = (const float*)d_in[9];
    const float* b1           = (const float*)d_in[10];
    const float* W2           = (const float*)d_in[11];
    const float* b2           = (const float*)d_in[12];
    float* out = (float*)d_out;

    ushort* p = (ushort*)d_ws;
    ushort* vB0 = p; p += (size_t)MM * DD;
    ushort* vB1 = p; p += (size_t)MM * DD;
    ushort* q0b = p; p += (size_t)MM * HR;
    ushort* q1b = p; p += (size_t)MM * HR;
    ushort* q2b = p; p += (size_t)MM * HR;
    ushort* k0b = p; p += (size_t)MM * HR;
    ushort* k1b = p; p += (size_t)MM * HR;
    ushort* k2b = p; p += (size_t)MM * HR;
    ushort* W1ph = p; p += 3 * 131072;
    ushort* W1pl = p; p += 3 * 131072;
    ushort* W2ph = p; p += 3 * 131072;
    ushort* W2pl = p; p += 3 * 131072;
    ushort* U0p = p; p += 3 * 32768;
    ushort* U1p = p; p += 3 * 32768;
    ushort* U2p = p; p += 3 * 32768;
    ushort* V0p = p; p += 3 * 32768;
    ushort* V1p = p; p += 3 * 32768;
    ushort* V2p = p; p += 3 * 32768;
    float* f = (float*)p;
    float* valA = f; f += (size_t)MM * DD;   // attention input (unit rows)
    float* valB = f; f += (size_t)MM * DD;   // attention output (f32)
    float* st0  = f; f += MM;
    float* st1  = f; f += MM;
    float* dst  = f; f += MM;

    pre_kernel<<<EMB_BLKS + 960, 256, 0, stream>>>(ids, emb, pos, anchor_val, anchor_state,
                                                   Ws, bs, valA, st0,
                                                   W1, W2, U, V,
                                                   W1ph, W1pl, W2ph, W2pl,
                                                   U0p, U1p, U2p, V0p, V1p, V2p);
    proj_kernel<<<dim3(257, 2), 256, 0, stream>>>(
        valA, U0p, U1p, U2p, V0p, V1p, V2p,
        q0b, q1b, q2b, k0b, k1b, k2b);

    float* s_in = st0;
    float* s_out = st1;
    for (int l = 0; l < 3; l++) {
        attn_kernel<<<BB * TB8, 256, 0, stream>>>(valA, s_in,
                                                  q0b, q1b, q2b, k0b, k1b, k2b,
                                                  valB, vB0, vB1, dst);
        int ln = (l < 2) ? (l + 1) : 0;   // next layer's U/V (unused when last)
        fusedF_kernel<<<131, 1024, 0, stream>>>(
            vB0, vB1, valB,
            W1ph + (size_t)l * 131072, W1pl + (size_t)l * 131072, b1 + (size_t)l * DFF,
            W2ph + (size_t)l * 131072, W2pl + (size_t)l * 131072, b2 + (size_t)l * DD,
            U0p + (size_t)ln * 32768, U1p + (size_t)ln * 32768, U2p + (size_t)ln * 32768,
            V0p + (size_t)ln * 32768, V1p + (size_t)ln * 32768, V2p + (size_t)ln * 32768,
            q0b, q1b, q2b, k0b, k1b, k2b,
            valA,
            s_in, dst, (l == 2) ? out : s_out,
            out + MM, (l == 2) ? 1 : 0);
        float* tmp = s_in; s_in = s_out; s_out = tmp;
    }
}

// Round 13
// 295.805 us; speedup vs baseline: 1.0605x; 1.0082x over previous
//
#include <hip/hip_runtime.h>
#include <hip/hip_bf16.h>
#include <math.h>

#define BB 2
#define SS 2048
#define NN 2049
#define MM (BB*NN)      // 4098 rows
#define DD 256
#define HR 128          // HEADS*RANK
#define NHEAD 4
#define DFF 512
#define EPSF 1e-6f
#define TB8 257
#define EMB_BLKS 1025   // ceil(MM/4)

typedef __attribute__((ext_vector_type(8))) short bf16x8;
typedef __attribute__((ext_vector_type(4))) float f32x4;

// ---------- helpers ----------
__device__ __forceinline__ float wave_sum(float v) {
    v += __shfl_down(v, 32, 64); v += __shfl_down(v, 16, 64);
    v += __shfl_down(v, 8, 64);  v += __shfl_down(v, 4, 64);
    v += __shfl_down(v, 2, 64);  v += __shfl_down(v, 1, 64);
    return v;
}
__device__ __forceinline__ float wave_max(float v) {
    v = fmaxf(v, __shfl_down(v, 32, 64)); v = fmaxf(v, __shfl_down(v, 16, 64));
    v = fmaxf(v, __shfl_down(v, 8, 64));  v = fmaxf(v, __shfl_down(v, 4, 64));
    v = fmaxf(v, __shfl_down(v, 2, 64));  v = fmaxf(v, __shfl_down(v, 1, 64));
    return v;
}
__device__ __forceinline__ float sgnf(float x) {
    return (x > 0.f) ? 1.f : ((x < 0.f) ? -1.f : 0.f);
}
__device__ __forceinline__ ushort f2b(float x) {
    __hip_bfloat16 h = __float2bfloat16(x);
    return *(ushort*)&h;
}
__device__ __forceinline__ float b2f(ushort u) {
    unsigned int v = ((unsigned int)u) << 16;
    return *(float*)&v;
}
__device__ __forceinline__ void split3(float x, ushort& h, ushort& m, ushort& l) {
    h = f2b(x);
    float r1 = x - b2f(h);
    m = f2b(r1);
    l = f2b(r1 - b2f(m));
}
__device__ __forceinline__ void pack_map(int e, int N, int& k, int& n) {
    int j = e & 7;
    int l = (e >> 3) & 63;
    int c = e >> 9;
    int ntiles = N >> 4;
    int kt = c / ntiles, nt = c - kt * ntiles;
    k = kt * 32 + ((l >> 4) << 3) + j;
    n = nt * 16 + (l & 15);
}
// async global->LDS DMA, 16B per lane
__device__ __forceinline__ void dma16(const ushort* g, ushort* lds) {
    __builtin_amdgcn_global_load_lds(
        (const __attribute__((address_space(1))) unsigned int*)g,
        (__attribute__((address_space(3))) unsigned int*)lds,
        16, 0, 0);
}

// =================== phase bodies ===================

__device__ __forceinline__ void pack_job(int idx,
    const float* __restrict__ W1, const float* __restrict__ W2,
    const float* __restrict__ U,  const float* __restrict__ V,
    ushort* __restrict__ W1ph, ushort* __restrict__ W1pl,
    ushort* __restrict__ W2ph, ushort* __restrict__ W2pl,
    ushort* __restrict__ U0, ushort* __restrict__ U1, ushort* __restrict__ U2,
    ushort* __restrict__ V0, ushort* __restrict__ V1, ushort* __restrict__ V2)
{
    int l = idx / 327680;
    int r = idx - l * 327680;
    if (l >= 3) return;
    int k, n;
    if (r < 131072) {
        int e = r;
        pack_map(e, 512, k, n);
        float s = W1[(size_t)l * 131072 + (size_t)k * 512 + n];
        ushort h = f2b(s);
        W1ph[(size_t)l * 131072 + e] = h;
        W1pl[(size_t)l * 131072 + e] = f2b(s - b2f(h));
    } else if (r < 262144) {
        int e = r - 131072;
        pack_map(e, 256, k, n);
        float s = W2[(size_t)l * 131072 + (size_t)k * 256 + n];
        ushort h = f2b(s);
        W2ph[(size_t)l * 131072 + e] = h;
        W2pl[(size_t)l * 131072 + e] = f2b(s - b2f(h));
    } else if (r < 294912) {
        int e = r - 262144;
        pack_map(e, 128, k, n);
        ushort h, m, lo;
        split3(U[(size_t)l * 32768 + (size_t)k * 128 + n], h, m, lo);
        U0[(size_t)l * 32768 + e] = h;
        U1[(size_t)l * 32768 + e] = m;
        U2[(size_t)l * 32768 + e] = lo;
    } else {
        int e = r - 294912;
        pack_map(e, 128, k, n);
        ushort h, m, lo;
        split3(V[(size_t)l * 32768 + (size_t)k * 128 + n], h, m, lo);
        V0[(size_t)l * 32768 + e] = h;
        V1[(size_t)l * 32768 + e] = m;
        V2[(size_t)l * 32768 + e] = lo;
    }
}

__device__ __forceinline__ void state_job(int b, int t, float* red,
    const float* __restrict__ state_in, const float* __restrict__ dstate,
    float* __restrict__ state_out)
{
    float lmax = -INFINITY;
    for (int n = t; n < NN; n += 256) {
        float x = state_in[b * NN + n] + dstate[b * NN + n];
        lmax = fmaxf(lmax, fabsf(x));
    }
    lmax = wave_max(lmax);
    if ((t & 63) == 0) red[t >> 6] = lmax;
    __syncthreads();
    float m = fmaxf(fmaxf(red[0], red[1]), fmaxf(red[2], red[3]));
    float lsum = 0.f;
    for (int n = t; n < NN; n += 256)
        lsum += expf(fabsf(state_in[b * NN + n] + dstate[b * NN + n]) - m);
    lsum = wave_sum(lsum);
    __syncthreads();
    if ((t & 63) == 0) red[4 + (t >> 6)] = lsum;
    __syncthreads();
    float inv = 1.f / (red[4] + red[5] + red[6] + red[7]);
    for (int n = t; n < NN; n += 256) {
        float x = state_in[b * NN + n] + dstate[b * NN + n];
        state_out[b * NN + n] = sgnf(x) * expf(fabsf(x) - m) * inv;
    }
}

// =================== pre: embed (4 rows/block, wave-per-row) + weight pack ===================

__global__ void pre_kernel(const int* __restrict__ ids, const float* __restrict__ emb,
                           const float* __restrict__ pos, const float* __restrict__ anchor_val,
                           const float* __restrict__ anchor_state, const float* __restrict__ Ws,
                           const float* __restrict__ bs, float* __restrict__ val,
                           float* __restrict__ state,
                           const float* __restrict__ W1, const float* __restrict__ W2,
                           const float* __restrict__ U,  const float* __restrict__ V,
                           ushort* W1ph, ushort* W1pl, ushort* W2ph, ushort* W2pl,
                           ushort* U0, ushort* U1, ushort* U2,
                           ushort* V0, ushort* V1, ushort* V2) {
    int bid = blockIdx.x;
    int t = threadIdx.x;
    if (bid < EMB_BLKS) {
        int w = t >> 6, l = t & 63;
        int row = bid * 4 + w;
        if (row >= MM) return;
        int b = row / NN, n = row % NN;
        f32x4 e;
        if (n == 0) {
            e = *(const f32x4*)(anchor_val + l * 4);
        } else {
            int id = ids[b * SS + (n - 1)];
            f32x4 em = *(const f32x4*)(emb + (size_t)id * DD + l * 4);
            f32x4 po = *(const f32x4*)(pos + (size_t)(n - 1) * DD + l * 4);
            e = em + po;
        }
        f32x4 wv = *(const f32x4*)(Ws + l * 4);
        float ss = e[0]*e[0] + e[1]*e[1] + e[2]*e[2] + e[3]*e[3];
        float ts = e[0]*wv[0] + e[1]*wv[1] + e[2]*wv[2] + e[3]*wv[3];
        #pragma unroll
        for (int off = 1; off < 64; off <<= 1) {
            ss += __shfl_xor(ss, off, 64);
            ts += __shfl_xor(ts, off, 64);
        }
        float rn = 1.f / fmaxf(sqrtf(ss), EPSF);
        f32x4 o;
        o[0] = e[0] * rn; o[1] = e[1] * rn; o[2] = e[2] * rn; o[3] = e[3] * rn;
        *(f32x4*)(val + (size_t)row * DD + l * 4) = o;
        if (l == 0) state[row] = (n == 0) ? anchor_state[0] : (ts + bs[0]);
        return;
    }
    int base = (bid - EMB_BLKS) * 1024 + t;
    #pragma unroll
    for (int k = 0; k < 4; k++)
        pack_job(base + k * 256, W1, W2, U, V,
                 W1ph, W1pl, W2ph, W2pl, U0, U1, U2, V0, V1, V2);
}

// =================== proj0: layer-0 q/k projection (input already unit rows) ===================

__global__ __launch_bounds__(256, 3)
void proj_kernel(const float* __restrict__ Xin,
                 const ushort* __restrict__ U0, const ushort* __restrict__ U1,
                 const ushort* __restrict__ U2,
                 const ushort* __restrict__ V0, const ushort* __restrict__ V1,
                 const ushort* __restrict__ V2,
                 ushort* __restrict__ q0, ushort* __restrict__ q1,
                 ushort* __restrict__ q2,
                 ushort* __restrict__ k0, ushort* __restrict__ k1,
                 ushort* __restrict__ k2) {
    __shared__ __align__(16) char smem[24576];   // 3 bf16 A-planes, XOR-swizzled
    int t = threadIdx.x;
    int w = t >> 6, l = t & 63;
    int lm = l & 15, quad = l >> 4;
    int m0 = blockIdx.x * 16;
    bool isQ = (blockIdx.y == 0);
    const ushort* P0 = isQ ? U0 : V0;
    const ushort* P1 = isQ ? U1 : V1;
    const ushort* P2 = isQ ? U2 : V2;

    #pragma unroll
    for (int rr = 0; rr < 4; rr++) {
        int row = w * 4 + rr;
        int tok = m0 + row; if (tok > MM - 1) tok = MM - 1;
        f32x4 x = *(const f32x4*)(Xin + (size_t)tok * DD + l * 4);
        ushort4 h4, m4, l4;
        ushort hh, mm, ll;
        split3(x[0], hh, mm, ll); h4.x = hh; m4.x = mm; l4.x = ll;
        split3(x[1], hh, mm, ll); h4.y = hh; m4.y = mm; l4.y = ll;
        split3(x[2], hh, mm, ll); h4.z = hh; m4.z = mm; l4.z = ll;
        split3(x[3], hh, mm, ll); h4.w = hh; m4.w = mm; l4.w = ll;
        unsigned byte = ((unsigned)(row * 512 + l * 8)) ^ ((unsigned)((row & 7) << 4));
        *(ushort4*)(smem + 0 * 8192 + byte) = h4;
        *(ushort4*)(smem + 1 * 8192 + byte) = m4;
        *(ushort4*)(smem + 2 * 8192 + byte) = l4;
    }
    __syncthreads();

    f32x4 acc[2];
    acc[0] = (f32x4)(0.f); acc[1] = (f32x4)(0.f);
    #pragma unroll
    for (int kt = 0; kt < 8; kt++) {
        unsigned abyte = ((unsigned)(lm * 512 + kt * 64 + quad * 16)) ^
                         ((unsigned)((lm & 7) << 4));
        bf16x8 a0 = *(const bf16x8*)(smem + 0 * 8192 + abyte);
        bf16x8 a1 = *(const bf16x8*)(smem + 1 * 8192 + abyte);
        bf16x8 a2 = *(const bf16x8*)(smem + 2 * 8192 + abyte);
        #pragma unroll
        for (int jj = 0; jj < 2; jj++) {
            int ntl = w * 2 + jj;
            size_t off = ((size_t)(kt * 8 + ntl) * 64 + l) * 8;
            bf16x8 b0 = *(const bf16x8*)(P0 + off);
            bf16x8 b1 = *(const bf16x8*)(P1 + off);
            bf16x8 b2 = *(const bf16x8*)(P2 + off);
            acc[jj] = __builtin_amdgcn_mfma_f32_16x16x32_bf16(a0, b0, acc[jj], 0, 0, 0);
            acc[jj] = __builtin_amdgcn_mfma_f32_16x16x32_bf16(a0, b1, acc[jj], 0, 0, 0);
            acc[jj] = __builtin_amdgcn_mfma_f32_16x16x32_bf16(a1, b0, acc[jj], 0, 0, 0);
            acc[jj] = __builtin_amdgcn_mfma_f32_16x16x32_bf16(a1, b1, acc[jj], 0, 0, 0);
            acc[jj] = __builtin_amdgcn_mfma_f32_16x16x32_bf16(a0, b2, acc[jj], 0, 0, 0);
            acc[jj] = __builtin_amdgcn_mfma_f32_16x16x32_bf16(a2, b0, acc[jj], 0, 0, 0);
        }
    }
    ushort* o0 = isQ ? q0 : k0;
    ushort* o1 = isQ ? q1 : k1;
    ushort* o2 = isQ ? q2 : k2;
    #pragma unroll
    for (int jj = 0; jj < 2; jj++) {
        int n = (w * 2 + jj) * 16 + lm;
        #pragma unroll
        for (int r = 0; r < 4; r++) {
            int tok = m0 + quad * 4 + r;
            if (tok < MM) {
                ushort h, m, lo;
                split3(acc[jj][r], h, m, lo);
                size_t oi = (size_t)tok * HR + n;
                o0[oi] = h; o1[oi] = m; o2[oi] = lo;
            }
        }
    }
}

// =================== attention (unchanged body) ===================

__global__ __launch_bounds__(256, 3)
void attn_kernel(const float* __restrict__ val_in,
                 const float* __restrict__ state_in,
                 const ushort* __restrict__ q0, const ushort* __restrict__ q1,
                 const ushort* __restrict__ q2,
                 const ushort* __restrict__ k0, const ushort* __restrict__ k1,
                 const ushort* __restrict__ k2,
                 float* __restrict__ val_out,
                 ushort* __restrict__ vbH, ushort* __restrict__ vbM,
                 float* __restrict__ dstate_out) {
    __shared__ float sc4[NHEAD][8][148];
    __shared__ float wgt2[144][12];
    __shared__ float redS[8][4];
    __shared__ float redM[8][4];

    int b = blockIdx.x / TB8;
    int n0 = (blockIdx.x % TB8) * 8;
    int t = threadIdx.x;
    int w = t >> 6, l = t & 63;
    int lm = l & 15, quad = l >> 4;

    {
        int qrow = n0 + (lm & 7);
        if (qrow > NN - 1) qrow = NN - 1;
        size_t qa = ((size_t)(b * NN + qrow)) * HR + w * 32 + quad * 8;
        bf16x8 a0 = *(const bf16x8*)(q0 + qa);
        bf16x8 a1 = *(const bf16x8*)(q1 + qa);
        bf16x8 a2 = *(const bf16x8*)(q2 + qa);
        #pragma unroll
        for (int jt = 0; jt < 9; jt++) {
            int j = n0 - 64 + jt * 16 + lm;
            j = (j < 0) ? 0 : ((j > NN - 1) ? NN - 1 : j);
            size_t ka = ((size_t)(b * NN + j)) * HR + w * 32 + quad * 8;
            bf16x8 kf0 = *(const bf16x8*)(k0 + ka);
            bf16x8 kf1 = *(const bf16x8*)(k1 + ka);
            bf16x8 kf2 = *(const bf16x8*)(k2 + ka);
            f32x4 acc = (f32x4)(0.f);
            acc = __builtin_amdgcn_mfma_f32_16x16x32_bf16(a0, kf0, acc, 0, 0, 0);
            acc = __builtin_amdgcn_mfma_f32_16x16x32_bf16(a0, kf1, acc, 0, 0, 0);
            acc = __builtin_amdgcn_mfma_f32_16x16x32_bf16(a1, kf0, acc, 0, 0, 0);
            acc = __builtin_amdgcn_mfma_f32_16x16x32_bf16(a1, kf1, acc, 0, 0, 0);
            acc = __builtin_amdgcn_mfma_f32_16x16x32_bf16(a0, kf2, acc, 0, 0, 0);
            acc = __builtin_amdgcn_mfma_f32_16x16x32_bf16(a2, kf0, acc, 0, 0, 0);
            if (quad < 2) {
                #pragma unroll
                for (int r = 0; r < 4; r++)
                    sc4[w][quad * 4 + r][jt * 16 + lm] = acc[r];
            }
        }
    }
    __syncthreads();

    {
        int m = t >> 5, p = t & 31;
        int n = n0 + m;
        bool tokv = (n < NN);
        float sv[5]; bool vv[5];
        float mx = -INFINITY;
        #pragma unroll
        for (int i = 0; i < 5; i++) {
            int tap = p + 32 * i;
            bool inb = (tap < 144);
            int tapc = inb ? tap : 0;
            int j = n0 - 64 + tapc;
            float s0 = sc4[0][m][tapc], s1 = sc4[1][m][tapc];
            float s2 = sc4[2][m][tapc], s3 = sc4[3][m][tapc];
            float s = fmaxf(fmaxf(s0, s1), fmaxf(s2, s3)) * 0.17677669529663687f;
            bool v = inb && tokv && (tap >= m) && (tap <= m + 128) && (j >= 0) && (j < NN);
            sv[i] = s; vv[i] = v;
            if (v) mx = fmaxf(mx, fabsf(s));
        }
        for (int off = 16; off > 0; off >>= 1) mx = fmaxf(mx, __shfl_xor(mx, off, 64));
        float ee[5];
        float sum = 0.f;
        #pragma unroll
        for (int i = 0; i < 5; i++) {
            ee[i] = vv[i] ? expf(fabsf(sv[i]) - mx) : 0.f;
            sum += ee[i];
        }
        for (int off = 16; off > 0; off >>= 1) sum += __shfl_xor(sum, off, 64);
        float inv = (sum > 0.f) ? 1.f / sum : 0.f;
        float ds = 0.f;
        #pragma unroll
        for (int i = 0; i < 5; i++) {
            int tap = p + 32 * i;
            if (tap < 144) {
                float wg = vv[i] ? sgnf(sv[i]) * ee[i] * inv : 0.f;
                wgt2[tap][m] = wg;
                if (vv[i]) ds += wg * state_in[b * NN + (n0 - 64 + tap)];
            }
        }
        for (int off = 16; off > 0; off >>= 1) ds += __shfl_xor(ds, off, 64);
        if (p == 0 && tokv) dstate_out[b * NN + n] = ds;
    }
    __syncthreads();

    {
        int d = (t >> 2) * 4;
        int tg = t & 3;
        int tok0 = tg * 2, tok1 = tg * 2 + 1;
        int jlo = (n0 >= 64) ? 0 : (64 - n0);
        int jhi = NN - 1 - n0 + 64; if (jhi > 135) jhi = 135;
        const float* vbase = val_in + ((size_t)(b * NN + n0 - 64)) * DD + d;
        f32x4 acc0 = (f32x4)(0.f), acc1 = (f32x4)(0.f);
        int jj = jlo;
        for (; jj + 3 <= jhi; jj += 4) {
            f32x4 v0 = *(const f32x4*)(vbase + (size_t)(jj + 0) * DD);
            f32x4 v1 = *(const f32x4*)(vbase + (size_t)(jj + 1) * DD);
            f32x4 v2 = *(const f32x4*)(vbase + (size_t)(jj + 2) * DD);
            f32x4 v3 = *(const f32x4*)(vbase + (size_t)(jj + 3) * DD);
            float wa0 = wgt2[jj + 0][tok0], wa1 = wgt2[jj + 0][tok1];
            float wb0 = wgt2[jj + 1][tok0], wb1 = wgt2[jj + 1][tok1];
            float wc0 = wgt2[jj + 2][tok0], wc1 = wgt2[jj + 2][tok1];
            float wd0 = wgt2[jj + 3][tok0], wd1 = wgt2[jj + 3][tok1];
            #pragma unroll
            for (int c = 0; c < 4; c++) {
                acc0[c] += v0[c] * wa0 + v1[c] * wb0 + v2[c] * wc0 + v3[c] * wd0;
                acc1[c] += v0[c] * wa1 + v1[c] * wb1 + v2[c] * wc1 + v3[c] * wd1;
            }
        }
        for (; jj <= jhi; jj++) {
            f32x4 v = *(const f32x4*)(vbase + (size_t)jj * DD);
            float w0 = wgt2[jj][tok0], w1 = wgt2[jj][tok1];
            #pragma unroll
            for (int c = 0; c < 4; c++) {
                acc0[c] += v[c] * w0;
                acc1[c] += v[c] * w1;
            }
        }
        f32x4 u[2]; f32x4 ac[2]; ac[0] = acc0; ac[1] = acc1;
        #pragma unroll
        for (int ti = 0; ti < 2; ti++) {
            int tok = tg * 2 + ti;
            int n = n0 + tok;
            f32x4 vold = (f32x4)(0.f);
            if (n < NN) vold = *(const f32x4*)(val_in + ((size_t)(b * NN + n)) * DD + d);
            u[ti] = vold + ac[ti];
            float s = u[ti][0]*u[ti][0] + u[ti][1]*u[ti][1] + u[ti][2]*u[ti][2] + u[ti][3]*u[ti][3];
            float mb = fmaxf(fmaxf(fabsf(ac[ti][0]), fabsf(ac[ti][1])),
                             fmaxf(fabsf(ac[ti][2]), fabsf(ac[ti][3])));
            for (int off = 4; off <= 32; off <<= 1) {
                s += __shfl_xor(s, off, 64);
                mb = fmaxf(mb, __shfl_xor(mb, off, 64));
            }
            if ((l >> 2) == 0) { redS[tok][w] = s; redM[tok][w] = mb; }
        }
        __syncthreads();
        #pragma unroll
        for (int ti = 0; ti < 2; ti++) {
            int tok = tg * 2 + ti;
            int n = n0 + tok;
            if (n < NN) {
                float ss = redS[tok][0] + redS[tok][1] + redS[tok][2] + redS[tok][3];
                float mab = fmaxf(fmaxf(redM[tok][0], redM[tok][1]),
                                  fmaxf(redM[tok][2], redM[tok][3]));
                float rn = 1.f / fmaxf(sqrtf(ss), EPSF);
                f32x4 o = u[ti];
                if (mab > 0.f) { o[0] *= rn; o[1] *= rn; o[2] *= rn; o[3] *= rn; }
                size_t oi = ((size_t)(b * NN + n)) * DD + d;
                *(f32x4*)(val_out + oi) = o;
                ushort4 hv, mv;
                {
                    ushort h0 = f2b(o[0]); hv.x = h0; mv.x = f2b(o[0] - b2f(h0));
                    ushort h1 = f2b(o[1]); hv.y = h1; mv.y = f2b(o[1] - b2f(h1));
                    ushort h2 = f2b(o[2]); hv.z = h2; mv.z = f2b(o[2] - b2f(h2));
                    ushort h3 = f2b(o[3]); hv.w = h3; mv.w = f2b(o[3] - b2f(h3));
                }
                *(ushort4*)(vbH + oi) = hv;
                *(ushort4*)(vbM + oi) = mv;
            }
        }
    }
}

// =================== fused F (1024 threads / 16 waves, 32-row strips):
//   two 8-wave tile-groups, each = one 16-row M-tile.
//   Phase A now LDS-stages W1h/W1l via global_load_lds double-buffer:
//   stg[2][64KB] at [0,128K) (free until H written). Both groups read the
//   same staged panels. One __syncthreads per kt: kt+1 DMA overlaps kt MFMA.
// LDS (131072 B): stg[2][64K] @0 during A; then Hh[2][16K] @0 | Hl @32K |
//   Y @64K ; phase C A-planes over [0,48K).

__global__ __launch_bounds__(1024, 1)
void fusedF_kernel(const ushort* __restrict__ vb0, const ushort* __restrict__ vb1,
                   const float*  __restrict__ valB,
                   const ushort* __restrict__ W1h, const ushort* __restrict__ W1l,
                   const float*  __restrict__ b1,
                   const ushort* __restrict__ W2h, const ushort* __restrict__ W2l,
                   const float*  __restrict__ b2,
                   const ushort* __restrict__ U0, const ushort* __restrict__ U1,
                   const ushort* __restrict__ U2,
                   const ushort* __restrict__ V0, const ushort* __restrict__ V1,
                   const ushort* __restrict__ V2,
                   ushort* __restrict__ q0, ushort* __restrict__ q1,
                   ushort* __restrict__ q2,
                   ushort* __restrict__ k0, ushort* __restrict__ k1,
                   ushort* __restrict__ k2,
                   float* __restrict__ valA,
                   const float* __restrict__ s_in, const float* __restrict__ dstate,
                   float* __restrict__ s_out,
                   float* __restrict__ out2, int last)
{
    __shared__ __align__(16) char smem[131072];
    int t = threadIdx.x;
    int bid = blockIdx.x;

    if (bid >= 129) {
        if (bid - 129 < BB) {
            if (t < 256) {
                state_job(bid - 129, t, (float*)smem, s_in, dstate, s_out);
            } else {
                __syncthreads(); __syncthreads(); __syncthreads();
            }
        }
        return;
    }

    int g  = t >> 9;                 // tile group 0/1
    int tl = t & 511;
    int w = tl >> 6, l = tl & 63;    // w in 0..7 within group
    int wg = t >> 6;                 // global wave 0..15
    int lm = l & 15, quad = l >> 4;
    int m0 = bid * 32 + g * 16;
    int row0 = m0 + lm; if (row0 > MM - 1) row0 = MM - 1;
    char* Hh_s = smem + g * 16384;
    char* Hl_s = smem + 32768 + g * 16384;
    char* Y_s  = smem + 65536 + g * 16384;
    char* P_s  = smem + g * 24576;   // phase C A-planes (alias over H region)

    // ---- phase A: ffn1 with W1 staged to LDS (dbuf, 64KB/kt) ----
    {
        const ushort* xh = vb0 + (size_t)row0 * DD + quad * 8;
        const ushort* xm = vb1 + (size_t)row0 * DD + quad * 8;
        f32x4 acc[4];
        #pragma unroll
        for (int jj = 0; jj < 4; jj++) acc[jj] = (f32x4)(0.f);

        // stage kt=0 into buf0: global wave wg stages panels p = wg*4+i
        #pragma unroll
        for (int i = 0; i < 4; i++) {
            int pp = wg * 4 + i;
            int plane = pp >> 5, nt = pp & 31;
            const ushort* src = (plane ? W1l : W1h) + (size_t)(0 * 32 + nt) * 512 + l * 8;
            dma16(src, (ushort*)(smem + plane * 32768 + nt * 1024) + l * 8);
        }
        __syncthreads();   // drains vmcnt -> buf0 ready

        #pragma unroll
        for (int kt = 0; kt < 8; kt++) {
            int cur = kt & 1;
            if (kt < 7) {
                #pragma unroll
                for (int i = 0; i < 4; i++) {
                    int pp = wg * 4 + i;
                    int plane = pp >> 5, nt = pp & 31;
                    const ushort* src = (plane ? W1l : W1h) +
                        (size_t)((kt + 1) * 32 + nt) * 512 + l * 8;
                    dma16(src, (ushort*)(smem + (cur ^ 1) * 65536 +
                                         plane * 32768 + nt * 1024) + l * 8);
                }
            }
            bf16x8 ah = *(const bf16x8*)(xh + kt * 32);
            bf16x8 am = *(const bf16x8*)(xm + kt * 32);
            char* stg = smem + cur * 65536;
            #pragma unroll
            for (int jj = 0; jj < 4; jj++) {
                int nt = w * 4 + jj;
                bf16x8 bh = *(const bf16x8*)(stg + nt * 1024 + l * 16);
                bf16x8 bl = *(const bf16x8*)(stg + 32768 + nt * 1024 + l * 16);
                acc[jj] = __builtin_amdgcn_mfma_f32_16x16x32_bf16(ah, bh, acc[jj], 0, 0, 0);
                acc[jj] = __builtin_amdgcn_mfma_f32_16x16x32_bf16(am, bh, acc[jj], 0, 0, 0);
                acc[jj] = __builtin_amdgcn_mfma_f32_16x16x32_bf16(ah, bl, acc[jj], 0, 0, 0);
            }
            __syncthreads();   // all reads of buf[cur] done; buf[cur^1] DMA drained
        }

        #pragma unroll
        for (int jj = 0; jj < 4; jj++) {
            int gn = (w * 4 + jj) * 16 + lm;
            float bb = b1[gn];
            #pragma unroll
            for (int r = 0; r < 4; r++) {
                int rho = quad * 4 + r;
                float x = acc[jj][r] + bb;
                float gl = 0.5f * x * (1.f + erff(x * 0.70710678118654752f));
                ushort gh = f2b(gl);
                unsigned byte = ((unsigned)(rho * 1024 + gn * 2)) ^
                                ((unsigned)((rho & 7) << 4));
                *(ushort*)(Hh_s + byte) = gh;
                *(ushort*)(Hl_s + byte) = f2b(gl - b2f(gh));
            }
        }
    }
    __syncthreads();

    // ---- phase B: ffn2 from LDS H -> Y (f32) in LDS (W2 direct from L2) ----
    {
        f32x4 acc[2];
        acc[0] = (f32x4)(0.f); acc[1] = (f32x4)(0.f);
        #pragma unroll
        for (int kt = 0; kt < 16; kt++) {
            unsigned ab = ((unsigned)(lm * 1024 + kt * 64 + quad * 16)) ^
                          ((unsigned)((lm & 7) << 4));
            bf16x8 ah = *(const bf16x8*)(Hh_s + ab);
            bf16x8 al = *(const bf16x8*)(Hl_s + ab);
            #pragma unroll
            for (int jj = 0; jj < 2; jj++) {
                int nt = w * 2 + jj;
                size_t off = ((size_t)(kt * 16 + nt) * 64 + l) * 8;
                bf16x8 bh = *(const bf16x8*)(W2h + off);
                bf16x8 bl = *(const bf16x8*)(W2l + off);
                acc[jj] = __builtin_amdgcn_mfma_f32_16x16x32_bf16(ah, bh, acc[jj], 0, 0, 0);
                acc[jj] = __builtin_amdgcn_mfma_f32_16x16x32_bf16(al, bh, acc[jj], 0, 0, 0);
                acc[jj] = __builtin_amdgcn_mfma_f32_16x16x32_bf16(ah, bl, acc[jj], 0, 0, 0);
            }
        }
        #pragma unroll
        for (int jj = 0; jj < 2; jj++) {
            int gn = (w * 2 + jj) * 16 + lm;
            float bb = b2[gn];
            #pragma unroll
            for (int r = 0; r < 4; r++) {
                int rho = quad * 4 + r;
                int tok = m0 + rho;
                int tokc = (tok > MM - 1) ? (MM - 1) : tok;
                float y = valB[(size_t)tokc * DD + gn] + acc[jj][r] + bb;
                unsigned byte = ((unsigned)(rho * 1024 + gn * 4)) ^
                                ((unsigned)((rho & 7) << 4));
                *(float*)(Y_s + byte) = y;
            }
        }
    }
    __syncthreads();

    // ---- phase C ----
    if (last) {
        #pragma unroll
        for (int rr = 0; rr < 2; rr++) {
            int row = w * 2 + rr;
            int tok = m0 + row;
            unsigned byte = ((unsigned)(row * 1024 + l * 16)) ^
                            ((unsigned)((row & 7) << 4));
            f32x4 y = *(const f32x4*)(Y_s + byte);
            float s = y[0]*y[0] + y[1]*y[1] + y[2]*y[2] + y[3]*y[3];
            #pragma unroll
            for (int off = 1; off < 64; off <<= 1) s += __shfl_xor(s, off, 64);
            float rn = 1.f / fmaxf(sqrtf(s), EPSF);
            if (tok < MM) {
                f32x4 o;
                o[0] = y[0] * rn; o[1] = y[1] * rn; o[2] = y[2] * rn; o[3] = y[3] * rn;
                *(f32x4*)(out2 + (size_t)tok * DD + l * 4) = o;
            }
        }
        return;
    }

    // next-layer input: norm rows, write valA, split3 -> A-planes (alias over H)
    #pragma unroll
    for (int rr = 0; rr < 2; rr++) {
        int row = w * 2 + rr;
        int tok = m0 + row;
        unsigned ybyte = ((unsigned)(row * 1024 + l * 16)) ^
                         ((unsigned)((row & 7) << 4));
        f32x4 x = *(const f32x4*)(Y_s + ybyte);
        float s = x[0]*x[0] + x[1]*x[1] + x[2]*x[2] + x[3]*x[3];
        #pragma unroll
        for (int off = 1; off < 64; off <<= 1) s += __shfl_xor(s, off, 64);
        float rn = 1.f / fmaxf(sqrtf(s), EPSF);
        x[0] *= rn; x[1] *= rn; x[2] *= rn; x[3] *= rn;
        if (tok < MM) *(f32x4*)(valA + (size_t)tok * DD + l * 4) = x;
        ushort4 h4, m4, l4;
        ushort hh, mm, ll;
        split3(x[0], hh, mm, ll); h4.x = hh; m4.x = mm; l4.x = ll;
        split3(x[1], hh, mm, ll); h4.y = hh; m4.y = mm; l4.y = ll;
        split3(x[2], hh, mm, ll); h4.z = hh; m4.z = mm; l4.z = ll;
        split3(x[3], hh, mm, ll); h4.w = hh; m4.w = mm; l4.w = ll;
        unsigned pbyte = ((unsigned)(row * 512 + l * 8)) ^ ((unsigned)((row & 7) << 4));
        *(ushort4*)(P_s + 0 * 8192 + pbyte) = h4;
        *(ushort4*)(P_s + 1 * 8192 + pbyte) = m4;
        *(ushort4*)(P_s + 2 * 8192 + pbyte) = l4;
    }
    __syncthreads();

    // q and k interleaved in ONE kt loop (per-acc MFMA order unchanged)
    {
        f32x4 aq = (f32x4)(0.f), ak = (f32x4)(0.f);
        #pragma unroll
        for (int kt = 0; kt < 8; kt++) {
            unsigned abyte = ((unsigned)(lm * 512 + kt * 64 + quad * 16)) ^
                             ((unsigned)((lm & 7) << 4));
            bf16x8 a0 = *(const bf16x8*)(P_s + 0 * 8192 + abyte);
            bf16x8 a1 = *(const bf16x8*)(P_s + 1 * 8192 + abyte);
            bf16x8 a2 = *(const bf16x8*)(P_s + 2 * 8192 + abyte);
            size_t off = ((size_t)(kt * 8 + w) * 64 + l) * 8;
            bf16x8 u0 = *(const bf16x8*)(U0 + off);
            bf16x8 u1 = *(const bf16x8*)(U1 + off);
            bf16x8 u2 = *(const bf16x8*)(U2 + off);
            bf16x8 v0 = *(const bf16x8*)(V0 + off);
            bf16x8 v1 = *(const bf16x8*)(V1 + off);
            bf16x8 v2 = *(const bf16x8*)(V2 + off);
            aq = __builtin_amdgcn_mfma_f32_16x16x32_bf16(a0, u0, aq, 0, 0, 0);
            ak = __builtin_amdgcn_mfma_f32_16x16x32_bf16(a0, v0, ak, 0, 0, 0);
            aq = __builtin_amdgcn_mfma_f32_16x16x32_bf16(a0, u1, aq, 0, 0, 0);
            ak = __builtin_amdgcn_mfma_f32_16x16x32_bf16(a0, v1, ak, 0, 0, 0);
            aq = __builtin_amdgcn_mfma_f32_16x16x32_bf16(a1, u0, aq, 0, 0, 0);
            ak = __builtin_amdgcn_mfma_f32_16x16x32_bf16(a1, v0, ak, 0, 0, 0);
            aq = __builtin_amdgcn_mfma_f32_16x16x32_bf16(a1, u1, aq, 0, 0, 0);
            ak = __builtin_amdgcn_mfma_f32_16x16x32_bf16(a1, v1, ak, 0, 0, 0);
            aq = __builtin_amdgcn_mfma_f32_16x16x32_bf16(a0, u2, aq, 0, 0, 0);
            ak = __builtin_amdgcn_mfma_f32_16x16x32_bf16(a0, v2, ak, 0, 0, 0);
            aq = __builtin_amdgcn_mfma_f32_16x16x32_bf16(a2, u0, aq, 0, 0, 0);
            ak = __builtin_amdgcn_mfma_f32_16x16x32_bf16(a2, v0, ak, 0, 0, 0);
        }
        int n = w * 16 + lm;
        #pragma unroll
        for (int r = 0; r < 4; r++) {
            int tok = m0 + quad * 4 + r;
            if (tok < MM) {
                ushort h, m, lo;
                size_t oi = (size_t)tok * HR + n;
                split3(aq[r], h, m, lo);
                q0[oi] = h; q1[oi] = m; q2[oi] = lo;
                split3(ak[r], h, m, lo);
                k0[oi] = h; k1[oi] = m; k2[oi] = lo;
            }
        }
    }
}

// =================== launcher ===================

extern "C" void kernel_launch(void* const* d_in, const int* in_sizes, int n_in,
                              void* d_out, int out_size, void* d_ws, size_t ws_size,
                              hipStream_t stream) {
    const int*   ids          = (const int*)d_in[0];
    const float* emb          = (const float*)d_in[1];
    const float* pos          = (const float*)d_in[2];
    const float* anchor_val   = (const float*)d_in[3];
    const float* anchor_state = (const float*)d_in[4];
    const float* Ws           = (const float*)d_in[5];
    const float* bs           = (const float*)d_in[6];
    const float* U            = (const float*)d_in[7];
    const float* V            = (const float*)d_in[8];
    const float* W1           = (const float*)d_in[9];
    const float* b1           = (const float*)d_in[10];
    const float* W2           = (const float*)d_in[11];
    const float* b2           = (const float*)d_in[12];
    float* out = (float*)d_out;

    ushort* p = (ushort*)d_ws;
    ushort* vB0 = p; p += (size_t)MM * DD;
    ushort* vB1 = p; p += (size_t)MM * DD;
    ushort* q0b = p; p += (size_t)MM * HR;
    ushort* q1b = p; p += (size_t)MM * HR;
    ushort* q2b = p; p += (size_t)MM * HR;
    ushort* k0b = p; p += (size_t)MM * HR;
    ushort* k1b = p; p += (size_t)MM * HR;
    ushort* k2b = p; p += (size_t)MM * HR;
    ushort* W1ph = p; p += 3 * 131072;
    ushort* W1pl = p; p += 3 * 131072;
    ushort* W2ph = p; p += 3 * 131072;
    ushort* W2pl = p; p += 3 * 131072;
    ushort* U0p = p; p += 3 * 32768;
    ushort* U1p = p; p += 3 * 32768;
    ushort* U2p = p; p += 3 * 32768;
    ushort* V0p = p; p += 3 * 32768;
    ushort* V1p = p; p += 3 * 32768;
    ushort* V2p = p; p += 3 * 32768;
    float* f = (float*)p;
    float* valA = f; f += (size_t)MM * DD;   // attention input (unit rows)
    float* valB = f; f += (size_t)MM * DD;   // attention output (f32)
    float* st0  = f; f += MM;
    float* st1  = f; f += MM;
    float* dst  = f; f += MM;

    pre_kernel<<<EMB_BLKS + 960, 256, 0, stream>>>(ids, emb, pos, anchor_val, anchor_state,
                                                   Ws, bs, valA, st0,
                                                   W1, W2, U, V,
                                                   W1ph, W1pl, W2ph, W2pl,
                                                   U0p, U1p, U2p, V0p, V1p, V2p);
    proj_kernel<<<dim3(257, 2), 256, 0, stream>>>(
        valA, U0p, U1p, U2p, V0p, V1p, V2p,
        q0b, q1b, q2b, k0b, k1b, k2b);

    float* s_in = st0;
    float* s_out = st1;
    for (int l = 0; l < 3; l++) {
        attn_kernel<<<BB * TB8, 256, 0, stream>>>(valA, s_in,
                                                  q0b, q1b, q2b, k0b, k1b, k2b,
                                                  valB, vB0, vB1, dst);
        int ln = (l < 2) ? (l + 1) : 0;   // next layer's U/V (unused when last)
        fusedF_kernel<<<131, 1024, 0, stream>>>(
            vB0, vB1, valB,
            W1ph + (size_t)l * 131072, W1pl + (size_t)l * 131072, b1 + (size_t)l * DFF,
            W2ph + (size_t)l * 131072, W2pl + (size_t)l * 131072, b2 + (size_t)l * DD,
            U0p + (size_t)ln * 32768, U1p + (size_t)ln * 32768, U2p + (size_t)ln * 32768,
            V0p + (size_t)ln * 32768, V1p + (size_t)ln * 32768, V2p + (size_t)ln * 32768,
            q0b, q1b, q2b, k0b, k1b, k2b,
            valA,
            s_in, dst, (l == 2) ? out : s_out,
            out + MM, (l == 2) ? 1 : 0);
        float* tmp = s_in; s_in = s_out; s_out = tmp;
    }
}